// Round 9
// baseline (10115.111 us; speedup 1.0000x reference)
//
#include <hip/hip_runtime.h>

#define IN_DIM   512
#define H_DIM    1024
#define OUT_DIM  256
#define B_DIM    64
#define S_DIM    256
#define EPS_F    1e-8f

#define BPG      8      // batches per group
#define NTHREADS 512
#define NWG      256    // one WG per CU (LDS pad; perf heuristic only)
#define SLOT_STRIDE 65536   // u32 elements per exchange slot
#define FLAGS_OFF  (2*SLOT_STRIDE)   // u32 index of flag array in hb

#define OUT_Y_TOTAL ((size_t)B_DIM*S_DIM*OUT_DIM)

typedef float    f32x4 __attribute__((ext_vector_type(4)));
typedef unsigned u32x4 __attribute__((ext_vector_type(4)));
typedef short    s16x8 __attribute__((ext_vector_type(8)));

#define MFMA16 __builtin_amdgcn_mfma_f32_16x16x32_bf16

union B8 { unsigned u[4]; s16x8 v; };

// split f32 -> (bf16 hi, bf16 lo) by truncation; hi+lo reconstructs ~2^-16 rel.
__device__ __forceinline__ void split_bf16(f32x4 f0, f32x4 f1, s16x8* hi, s16x8* lo) {
  B8 H, L;
  float fv[8];
#pragma unroll
  for (int e = 0; e < 4; ++e) { fv[e] = f0[e]; fv[e+4] = f1[e]; }
#pragma unroll
  for (int d = 0; d < 4; ++d) {
    unsigned u0 = __float_as_uint(fv[2*d]);
    unsigned u1 = __float_as_uint(fv[2*d+1]);
    unsigned t0 = u0 & 0xffff0000u, t1 = u1 & 0xffff0000u;
    H.u[d] = (u0 >> 16) | t1;
    L.u[d] = ((__float_as_uint(fv[2*d]   - __uint_as_float(t0))) >> 16)
           | ((__float_as_uint(fv[2*d+1] - __uint_as_float(t1))) & 0xffff0000u);
  }
  *hi = H.v; *lo = L.v;
}

// exchange word per (b,j): [hi bf16 | lo bf16] (full precision; flags gate validity)
__device__ __forceinline__ u32x4 enc_h(f32x4 hn) {
  u32x4 e;
#pragma unroll
  for (int k = 0; k < 4; ++k) {
    unsigned uh = __float_as_uint(hn[k]) & 0xFFFF0000u;
    float r = hn[k] - __uint_as_float(uh);
    e[k] = uh | (__float_as_uint(r) >> 16);
  }
  return e;
}
__device__ __forceinline__ s16x8 pack_hi(u32x4 a, u32x4 b) {
  B8 t;
  t.u[0] = (a.y & 0xFFFF0000u) | (a.x >> 16);
  t.u[1] = (a.w & 0xFFFF0000u) | (a.z >> 16);
  t.u[2] = (b.y & 0xFFFF0000u) | (b.x >> 16);
  t.u[3] = (b.w & 0xFFFF0000u) | (b.z >> 16);
  return t.v;
}
__device__ __forceinline__ s16x8 pack_lo(u32x4 a, u32x4 b) {
  B8 t;
  t.u[0] = (a.y << 16) | (a.x & 0xFFFFu);
  t.u[1] = (a.w << 16) | (a.z & 0xFFFFu);
  t.u[2] = (b.y << 16) | (b.x & 0xFFFFu);
  t.u[3] = (b.w << 16) | (b.z & 0xFFFFu);
  return t.v;
}

__global__ void __launch_bounds__(NTHREADS)
ltc_kernel(const float* __restrict__ x, const float* __restrict__ h0,
           const float* __restrict__ tspan, const float* __restrict__ tau,
           const float* __restrict__ Wiw, const float* __restrict__ Wib,
           const float* __restrict__ Wrw, const float* __restrict__ wmask,
           const float* __restrict__ Wow, const float* __restrict__ Wob,
           const float* __restrict__ alpha_p, const float* __restrict__ beta_p,
           const float* __restrict__ mu_p, const float* __restrict__ sigma_p,
           float* __restrict__ out, unsigned* __restrict__ hb)
{
  __shared__ __align__(16) float sch[2][8][8][36];  // [slot][kp][b][j] h partials
  __shared__ __align__(16) float scx[8][8][36];     // iin partials
  __shared__ __align__(16) float scy[8][8][9];      // y partials
  __shared__ char lds_pad[57344];   // spread 1 WG/CU (perf only; no correctness dep)

  const int tid = threadIdx.x;
  ((volatile char*)lds_pad)[tid] = 0;

  const int wg  = blockIdx.x;
  const int g   = wg & 7;           // group (XCD heuristic; correctness-independent)
  const int w   = wg >> 3;          // 0..31 j-slice within group
  const int b0g = g * BPG;
  const int jw0 = w * 32;
  const int l   = tid & 63;
  const int v   = tid >> 6;         // wave id: K-part (consumer), batch owner (producer)
  const int gb_v = b0g + v;
  const int le  = l & 7;
  const int j4  = jw0 + 4*le;

  unsigned* flags = hb + FLAGS_OFF;         // [8 g][32 w] phase counters
  const unsigned* fp4 = flags + g*32 + 4*v; // this wave's 4 producers (16B aligned)

  // ---- W_rec B-frags (masked, split bf16) -> registers, permanent
  s16x8 wbh[4][2], wbl[4][2];
#pragma unroll
  for (int i = 0; i < 4; ++i) {
    const int k0 = v*128 + i*32 + ((l >> 4) << 3);
#pragma unroll
    for (int nt = 0; nt < 2; ++nt) {
      const size_t go = (size_t)(jw0 + nt*16 + (l & 15))*H_DIM + k0;
      f32x4 w0 = *(const f32x4*)(Wrw + go)     * *(const f32x4*)(wmask + go);
      f32x4 w1 = *(const f32x4*)(Wrw + go + 4) * *(const f32x4*)(wmask + go + 4);
      split_bf16(w0, w1, &wbh[i][nt], &wbl[i][nt]);
    }
  }

  // ---- per-lane (lanes 0..7) epilogue state for batch b=v
  f32x4 mu4  = *(const f32x4*)(mu_p + j4);
  f32x4 sg4  = *(const f32x4*)(sigma_p + j4);
  f32x4 al4  = *(const f32x4*)(alpha_p + j4);
  f32x4 be4  = *(const f32x4*)(beta_p + j4);
  f32x4 ta4  = *(const f32x4*)(tau + j4);
  f32x4 wib4 = *(const f32x4*)(Wib + j4);
  f32x4 sgi4, ti4;
#pragma unroll
  for (int e = 0; e < 4; ++e) { sgi4[e] = 1.0f/(sg4[e]+EPS_F); ti4[e] = 1.0f/ta4[e]; }
  const float wob_s = Wob[w*8 + le];
  f32x4 hold4 = *(const f32x4*)(h0 + ((size_t)gb_v << 10) + j4);
  float tsc = tspan[(size_t)gb_v*S_DIM] * (1.0f/6.0f);

  // ---- publish h slice to MALL (data only; release = flag store after barrier)
  auto store_h = [&](f32x4 hn, unsigned slot) {
    u32x4 enc = enc_h(hn);
    unsigned* dst = hb + slot*SLOT_STRIDE + ((unsigned)gb_v << 10) + j4;
    asm volatile("global_store_dwordx4 %0, %1, off sc0 sc1"
                 :: "v"(dst), "v"(enc) : "memory");
  };
  // release: all h stores of this WG are MALL-acked before tid0 raises the flag
  auto release = [&](unsigned fval) {
    asm volatile("s_waitcnt vmcnt(0)" ::: "memory");
    __syncthreads();
    if (tid == 0) {
      unsigned* fdst = flags + g*32 + w;
      asm volatile("global_store_dword %0, %1, off sc0 sc1"
                   :: "v"(fdst), "v"(fval) : "memory");
    }
  };

  // ---- phase 0: h0 -> slot 0; flag = 1
  if (l < 8) store_h(hold4, 0u);
  release(1u);

  // ---- acquire: poll 4 producer flags (16B/round), then load fragment ONCE
  auto acquire = [&](unsigned need, unsigned slotC,
                     u32x4& q0, u32x4& q1, u32x4& q2, u32x4& q3,
                     u32x4& q4, u32x4& q5, u32x4& q6, u32x4& q7) {
    for (;;) {
      u32x4 f;
      asm volatile("global_load_dwordx4 %0, %1, off sc0 sc1\n\ts_waitcnt vmcnt(0)"
                   : "=v"(f) : "v"(fp4) : "memory");
      if (f.x >= need && f.y >= need && f.z >= need && f.w >= need) break;
      __builtin_amdgcn_s_sleep(2);
    }
    const unsigned* ap = hb + slotC*SLOT_STRIDE
                       + ((unsigned)(b0g + (l & 7)) << 10)
                       + (unsigned)(v*128 + ((l >> 4) << 3));
    if ((l & 15) < 8) {
      asm volatile(
        "global_load_dwordx4 %0, %8, off sc0 sc1\n\t"
        "global_load_dwordx4 %1, %8, off offset:16 sc0 sc1\n\t"
        "global_load_dwordx4 %2, %8, off offset:128 sc0 sc1\n\t"
        "global_load_dwordx4 %3, %8, off offset:144 sc0 sc1\n\t"
        "global_load_dwordx4 %4, %8, off offset:256 sc0 sc1\n\t"
        "global_load_dwordx4 %5, %8, off offset:272 sc0 sc1\n\t"
        "global_load_dwordx4 %6, %8, off offset:384 sc0 sc1\n\t"
        "global_load_dwordx4 %7, %8, off offset:400 sc0 sc1\n\t"
        "s_waitcnt vmcnt(0)"
        : "=&v"(q0), "=&v"(q1), "=&v"(q2), "=&v"(q3),
          "=&v"(q4), "=&v"(q5), "=&v"(q6), "=&v"(q7)
        : "v"(ap) : "memory");
    }
  };

  // ---- iin partial MFMA (x, Win plain cached loads)
  auto iin_partials = [&](int tt, f32x4& ax0, f32x4& ax1) {
    const int bL = l & 7, ko = (l >> 4) << 3;
    const float* xp = x + ((size_t)(b0g + bL)*S_DIM + tt)*IN_DIM + v*64 + ko;
    f32x4 xq0 = *(const f32x4*)xp,        xq1 = *(const f32x4*)(xp + 4);
    f32x4 xq2 = *(const f32x4*)(xp + 32), xq3 = *(const f32x4*)(xp + 36);
    const int jn0 = jw0 + (l & 15);
#pragma unroll
    for (int i2 = 0; i2 < 2; ++i2) {
      s16x8 xh, xl;
      split_bf16(i2 ? xq2 : xq0, i2 ? xq3 : xq1, &xh, &xl);
#pragma unroll
      for (int nt = 0; nt < 2; ++nt) {
        const float* wp = Wiw + (size_t)(jn0 + nt*16)*IN_DIM + v*64 + i2*32 + ko;
        s16x8 wh, wl;
        split_bf16(*(const f32x4*)wp, *(const f32x4*)(wp + 4), &wh, &wl);
        if (nt == 0) {
          ax0 = MFMA16(xh, wh, ax0, 0,0,0);
          ax0 = MFMA16(xl, wh, ax0, 0,0,0);
          ax0 = MFMA16(xh, wl, ax0, 0,0,0);
        } else {
          ax1 = MFMA16(xh, wh, ax1, 0,0,0);
          ax1 = MFMA16(xl, wh, ax1, 0,0,0);
          ax1 = MFMA16(xh, wl, ax1, 0,0,0);
        }
      }
    }
  };

  auto load_wout = [&](s16x8 woY[4], s16x8 wlY[4]) {
    B8 z; z.u[0] = z.u[1] = z.u[2] = z.u[3] = 0;
#pragma unroll
    for (int i = 0; i < 4; ++i) { woY[i] = z.v; wlY[i] = z.v; }
    if ((l & 15) < 8) {
#pragma unroll
      for (int i = 0; i < 4; ++i) {
        const int k0 = v*128 + i*32 + ((l >> 4) << 3);
        const size_t go = (size_t)(w*8 + (l & 15))*H_DIM + k0;
        split_bf16(*(const f32x4*)(Wow + go), *(const f32x4*)(Wow + go + 4),
                   &woY[i], &wlY[i]);
      }
    }
  };

  // ---- pre-loop: iin(0) -> registers
  f32x4 iin4 = {0.f,0.f,0.f,0.f}, iin_nx = {0.f,0.f,0.f,0.f};
  {
    f32x4 ax0 = {0.f,0.f,0.f,0.f}, ax1 = {0.f,0.f,0.f,0.f};
    iin_partials(0, ax0, ax1);
    if (l < 32) {
      const int brow = (l >> 4) * 4, l15 = l & 15;
      float* scxp = &scx[v][brow][l15];
#pragma unroll
      for (int qq = 0; qq < 4; ++qq) { scxp[qq*36] = ax0[qq]; scxp[qq*36 + 16] = ax1[qq]; }
    }
    __syncthreads();
    if (l < 8) {
      f32x4 s = wib4;
#pragma unroll
      for (int k2 = 0; k2 < 8; ++k2) s += *(const f32x4*)&scx[k2][v][4*le];
      iin4 = s;
    }
    __syncthreads();
  }

  unsigned p = 1;
#pragma unroll 1
  for (int t = 0; t < S_DIM; ++t) {
#pragma unroll 1
    for (int u = 0; u < 6; ++u, ++p) {
      const unsigned slotC = (p-1) & 1;   // consume phase p-1
      const unsigned slotP = p & 1;       // publish phase p
      const bool doY = (u == 0);
      const bool doX = (u == 3) && (t + 1 < S_DIM);

      s16x8 woY[4], wlY[4];
      if (doY) load_wout(woY, wlY);   // cached loads; overlap with flag spin

      u32x4 q0,q1,q2,q3,q4,q5,q6,q7;
      acquire(p, slotC, q0,q1,q2,q3,q4,q5,q6,q7);   // need flag >= p (phase p-1 done)

      // ---- MFMA: 3-split bf16 (hh + lh + hl), B from registers
      f32x4 acc0 = {0.f,0.f,0.f,0.f}, acc1 = {0.f,0.f,0.f,0.f};
      f32x4 accy = {0.f,0.f,0.f,0.f};
#pragma unroll
      for (int i = 0; i < 4; ++i) {
        u32x4 qa = (i==0) ? q0 : (i==1) ? q2 : (i==2) ? q4 : q6;
        u32x4 qb = (i==0) ? q1 : (i==1) ? q3 : (i==2) ? q5 : q7;
        s16x8 ah = pack_hi(qa, qb), al = pack_lo(qa, qb);
        acc0 = MFMA16(ah, wbh[i][0], acc0, 0,0,0);
        acc0 = MFMA16(al, wbh[i][0], acc0, 0,0,0);
        acc0 = MFMA16(ah, wbl[i][0], acc0, 0,0,0);
        acc1 = MFMA16(ah, wbh[i][1], acc1, 0,0,0);
        acc1 = MFMA16(al, wbh[i][1], acc1, 0,0,0);
        acc1 = MFMA16(ah, wbl[i][1], acc1, 0,0,0);
        if (doY) {
          accy = MFMA16(ah, woY[i], accy, 0,0,0);
          accy = MFMA16(al, woY[i], accy, 0,0,0);
          accy = MFMA16(ah, wlY[i], accy, 0,0,0);
        }
      }
      f32x4 ax0 = {0.f,0.f,0.f,0.f}, ax1 = {0.f,0.f,0.f,0.f};
      if (doX) iin_partials(t + 1, ax0, ax1);

      // ---- partials -> LDS scratch
      if (l < 32) {
        const int brow = (l >> 4) * 4, l15 = l & 15;
        float* schp = &sch[slotP][v][brow][l15];
#pragma unroll
        for (int qq = 0; qq < 4; ++qq) { schp[qq*36] = acc0[qq]; schp[qq*36 + 16] = acc1[qq]; }
        if (doX) {
          float* scxp = &scx[v][brow][l15];
#pragma unroll
          for (int qq = 0; qq < 4; ++qq) { scxp[qq*36] = ax0[qq]; scxp[qq*36 + 16] = ax1[qq]; }
        }
        if (doY && l15 < 8) {
          float* scyp = &scy[v][brow][l15];
#pragma unroll
          for (int qq = 0; qq < 4; ++qq) scyp[qq*9] = accy[qq];
        }
      }
      __syncthreads();

      // ---- distributed epilogue: wave v owns batch b=v (lanes 0..7)
      if (l < 8) {
        f32x4 ir = {0.f,0.f,0.f,0.f};
#pragma unroll
        for (int k2 = 0; k2 < 8; ++k2) ir += *(const f32x4*)&sch[slotP][k2][v][4*le];
        f32x4 hn;
#pragma unroll
        for (int e = 0; e < 4; ++e) {
          const float z  = (ir[e] - mu4[e]) * sgi4[e];
          const float f  = 1.0f / (1.0f + __expf(-z));
          const float dh = -al4[e]*hold4[e] + be4[e]*f*(iin4[e] + ir[e]);
          hn[e] = hold4[e] + tsc*dh*ti4[e];
        }
        hold4 = hn;
        store_h(hn, slotP);
        if (doY && t > 0) {
          float s = wob_s;
#pragma unroll
          for (int k2 = 0; k2 < 8; ++k2) s += scy[k2][v][le];
          out[((size_t)gb_v*S_DIM + (t-1))*OUT_DIM + w*8 + le] = s;
        }
        if (doX) {
          f32x4 s = wib4;
#pragma unroll
          for (int k2 = 0; k2 < 8; ++k2) s += *(const f32x4*)&scx[k2][v][4*le];
          iin_nx = s;
        }
        if (u == 5) {
          if (t + 1 < S_DIM) {
            tsc = tspan[(size_t)gb_v*S_DIM + t + 1] * (1.0f/6.0f);
            iin4 = iin_nx;
          } else {
            *(f32x4*)(out + OUT_Y_TOTAL + ((size_t)gb_v << 10) + j4) = hn;
          }
        }
      }
      release(p + 1);   // vmcnt drain + barrier + tid0 flag store
    }
  }

  // ---- tail: y(S-1) from final h (phase 1536, flag 1537)
  {
    const unsigned slotC = (p-1) & 1;
    s16x8 woY[4], wlY[4];
    load_wout(woY, wlY);
    u32x4 q0,q1,q2,q3,q4,q5,q6,q7;
    acquire(p, slotC, q0,q1,q2,q3,q4,q5,q6,q7);
    f32x4 accy = {0.f,0.f,0.f,0.f};
#pragma unroll
    for (int i = 0; i < 4; ++i) {
      u32x4 qa = (i==0) ? q0 : (i==1) ? q2 : (i==2) ? q4 : q6;
      u32x4 qb = (i==0) ? q1 : (i==1) ? q3 : (i==2) ? q5 : q7;
      s16x8 ah = pack_hi(qa, qb), al = pack_lo(qa, qb);
      accy = MFMA16(ah, woY[i], accy, 0,0,0);
      accy = MFMA16(al, woY[i], accy, 0,0,0);
      accy = MFMA16(ah, wlY[i], accy, 0,0,0);
    }
    if (l < 32 && (l & 15) < 8) {
      const int brow = (l >> 4) * 4, l15 = l & 15;
      float* scyp = &scy[v][brow][l15];
#pragma unroll
      for (int qq = 0; qq < 4; ++qq) scyp[qq*9] = accy[qq];
    }
    __syncthreads();
    if (l < 8) {
      float s = wob_s;
#pragma unroll
      for (int k2 = 0; k2 < 8; ++k2) s += scy[k2][v][le];
      out[((size_t)gb_v*S_DIM + (S_DIM-1))*OUT_DIM + w*8 + le] = s;
    }
  }
}

extern "C" void kernel_launch(void* const* d_in, const int* in_sizes, int n_in,
                              void* d_out, int out_size, void* d_ws, size_t ws_size,
                              hipStream_t stream) {
  const float* x    = (const float*)d_in[0];
  const float* h0   = (const float*)d_in[1];
  const float* ts   = (const float*)d_in[2];
  const float* tau  = (const float*)d_in[3];
  const float* Wiw  = (const float*)d_in[4];
  const float* Wib  = (const float*)d_in[5];
  const float* Wrw  = (const float*)d_in[6];
  const float* msk  = (const float*)d_in[7];
  const float* Wow  = (const float*)d_in[8];
  const float* Wob  = (const float*)d_in[9];
  const float* alp  = (const float*)d_in[10];
  const float* bet  = (const float*)d_in[11];
  const float* mu   = (const float*)d_in[12];
  const float* sg   = (const float*)d_in[13];
  float* out = (float*)d_out;
  unsigned* hb = (unsigned*)d_ws;   // [0,512KB) h slots | [512KB,+1KB) flags

  // reset flags (phase counters) every launch -> replay-deterministic
  hipMemsetAsync(hb + FLAGS_OFF, 0, 256*sizeof(unsigned), stream);

  void* args[] = { (void*)&x, (void*)&h0, (void*)&ts, (void*)&tau,
                   (void*)&Wiw, (void*)&Wib, (void*)&Wrw, (void*)&msk,
                   (void*)&Wow, (void*)&Wob, (void*)&alp, (void*)&bet,
                   (void*)&mu, (void*)&sg, (void*)&out, (void*)&hb };
  hipLaunchCooperativeKernel((const void*)ltc_kernel, dim3(NWG), dim3(NTHREADS),
                             args, 0, stream);
}

// Round 10
// 9586.403 us; speedup vs baseline: 1.0552x; 1.0552x over previous
//
#include <hip/hip_runtime.h>

#define IN_DIM   512
#define H_DIM    1024
#define OUT_DIM  256
#define B_DIM    64
#define S_DIM    256
#define EPS_F    1e-8f

#define BPG      4      // batches per group
#define JPW      64     // j-columns per WG
#define NTHREADS 512
#define NWG      256    // one WG per CU (LDS pad)
#define SLOT_STRIDE 65536   // u32 elements per exchange slot

#define OUT_Y_TOTAL ((size_t)B_DIM*S_DIM*OUT_DIM)

typedef float    f32x4 __attribute__((ext_vector_type(4)));
typedef unsigned u32x4 __attribute__((ext_vector_type(4)));
typedef short    s16x8 __attribute__((ext_vector_type(8)));

#define MFMA16 __builtin_amdgcn_mfma_f32_16x16x32_bf16

union B8 { unsigned u[4]; s16x8 v; };

// split f32 -> (bf16 hi, bf16 lo) by truncation; hi+lo reconstructs ~2^-16 rel.
__device__ __forceinline__ void split_bf16(f32x4 f0, f32x4 f1, s16x8* hi, s16x8* lo) {
  B8 H, L;
  float fv[8];
#pragma unroll
  for (int e = 0; e < 4; ++e) { fv[e] = f0[e]; fv[e+4] = f1[e]; }
#pragma unroll
  for (int d = 0; d < 4; ++d) {
    unsigned u0 = __float_as_uint(fv[2*d]);
    unsigned u1 = __float_as_uint(fv[2*d+1]);
    unsigned t0 = u0 & 0xffff0000u, t1 = u1 & 0xffff0000u;
    H.u[d] = (u0 >> 16) | t1;
    L.u[d] = ((__float_as_uint(fv[2*d]   - __uint_as_float(t0))) >> 16)
           | ((__float_as_uint(fv[2*d+1] - __uint_as_float(t1))) & 0xffff0000u);
  }
  *hi = H.v; *lo = L.v;
}

// 12-bit phase tag spread 3 bits per word of each 16B granule (R7-proven).
__device__ __forceinline__ unsigned dec_tag(u32x4 q) {
  return (q.x & 7u) | ((q.y & 7u) << 3) | ((q.z & 7u) << 6) | ((q.w & 7u) << 9);
}
__device__ __forceinline__ s16x8 pack_hi(u32x4 a, u32x4 b) {
  B8 t;
  t.u[0] = (a.y & 0xFFFF0000u) | (a.x >> 16);
  t.u[1] = (a.w & 0xFFFF0000u) | (a.z >> 16);
  t.u[2] = (b.y & 0xFFFF0000u) | (b.x >> 16);
  t.u[3] = (b.w & 0xFFFF0000u) | (b.z >> 16);
  return t.v;
}
__device__ __forceinline__ s16x8 pack_lo(u32x4 a, u32x4 b) {
  B8 t;   // strip 3 stolen tag bits from every residual word
  t.u[0] = ((a.y & 0xFFF8u) << 16) | (a.x & 0xFFF8u);
  t.u[1] = ((a.w & 0xFFF8u) << 16) | (a.z & 0xFFF8u);
  t.u[2] = ((b.y & 0xFFF8u) << 16) | (b.x & 0xFFF8u);
  t.u[3] = ((b.w & 0xFFF8u) << 16) | (b.z & 0xFFF8u);
  return t.v;
}

#define POLL_BODY(FLAGS)                                                      \
  asm volatile(                                                               \
    "global_load_dwordx4 %0, %8, off " FLAGS "\n\t"                           \
    "global_load_dwordx4 %1, %8, off offset:16 " FLAGS "\n\t"                 \
    "global_load_dwordx4 %2, %8, off offset:128 " FLAGS "\n\t"                \
    "global_load_dwordx4 %3, %8, off offset:144 " FLAGS "\n\t"                \
    "global_load_dwordx4 %4, %8, off offset:256 " FLAGS "\n\t"                \
    "global_load_dwordx4 %5, %8, off offset:272 " FLAGS "\n\t"                \
    "global_load_dwordx4 %6, %8, off offset:384 " FLAGS "\n\t"                \
    "global_load_dwordx4 %7, %8, off offset:400 " FLAGS "\n\t"                \
    "s_waitcnt vmcnt(0)"                                                      \
    : "=&v"(q0), "=&v"(q1), "=&v"(q2), "=&v"(q3),                             \
      "=&v"(q4), "=&v"(q5), "=&v"(q6), "=&v"(q7)                              \
    : "v"(ap) : "memory")

__global__ void __launch_bounds__(NTHREADS)
ltc_kernel(const float* __restrict__ x, const float* __restrict__ h0,
           const float* __restrict__ tspan, const float* __restrict__ tau,
           const float* __restrict__ Wiw, const float* __restrict__ Wib,
           const float* __restrict__ Wrw, const float* __restrict__ wmask,
           const float* __restrict__ Wow, const float* __restrict__ Wob,
           const float* __restrict__ alpha_p, const float* __restrict__ beta_p,
           const float* __restrict__ mu_p, const float* __restrict__ sigma_p,
           float* __restrict__ out, unsigned* __restrict__ hb)
{
  __shared__ float sch[2][8][4][68];   // [slot][kp][b][j] h partials (17408 B)
  __shared__ float scx[8][4][68];      // iin partials (8704 B)
  __shared__ float scy[8][4][20];      // y partials (2560 B)
  __shared__ char lds_pad[57344];      // 1 WG/CU (perf only; no correctness dep)

  const int tid = threadIdx.x;
  ((volatile char*)lds_pad)[tid] = 0;

  const int wg  = blockIdx.x;
  const int g   = wg >> 4;          // group: 4 batches
  const int w   = wg & 15;          // j-slice (64 cols) within group
  const int b0g = g * BPG;
  const int jw0 = w * JPW;
  const int l   = tid & 63;
  const int v   = tid >> 6;         // wave id = K-part (k in [128v,128v+128))
  const int vb  = v & 3;
  const int gb_e = b0g + vb;        // epilogue batch (waves 0..3 only)
  const int gj  = jw0 + l;          // epilogue column (1/lane)

  // ---- W_rec B-frags (masked, split bf16) -> registers, permanent (128 VGPR)
  s16x8 wbh[4][4], wbl[4][4];
#pragma unroll
  for (int i = 0; i < 4; ++i) {
    const int k0 = v*128 + i*32 + ((l >> 4) << 3);
#pragma unroll
    for (int nt = 0; nt < 4; ++nt) {
      const size_t go = (size_t)(jw0 + nt*16 + (l & 15))*H_DIM + k0;
      f32x4 w0 = *(const f32x4*)(Wrw + go)     * *(const f32x4*)(wmask + go);
      f32x4 w1 = *(const f32x4*)(Wrw + go + 4) * *(const f32x4*)(wmask + go + 4);
      split_bf16(w0, w1, &wbh[i][nt], &wbl[i][nt]);
    }
  }

  // ---- per-thread epilogue state: (b = v, j = lane), scalar
  const float mu_s  = mu_p[gj];
  const float sgi_s = 1.0f / (sigma_p[gj] + EPS_F);
  const float al_s  = alpha_p[gj];
  const float be_s  = beta_p[gj];
  const float ti_s  = 1.0f / tau[gj];
  const float wib_s = Wib[gj];
  float hold_s = h0[((size_t)gb_e << 10) + gj];
  float tsc = tspan[(size_t)gb_e*S_DIM] * (1.0f/6.0f);

  // ---- publish one h element (tag piece by j%4; R7 encoding)
  auto store_h = [&](float hn, unsigned slot, unsigned tag) {
    unsigned uh = __float_as_uint(hn) & 0xFFFF0000u;
    float r = hn - __uint_as_float(uh);
    unsigned e = (uh | (__float_as_uint(r) >> 16)) & ~7u;
    e |= (tag >> (3*(l & 3))) & 7u;
    unsigned* dst = hb + slot*SLOT_STRIDE + ((unsigned)gb_e << 10) + (unsigned)gj;
    asm volatile("global_store_dword %0, %1, off sc0 sc1"
                 :: "v"(dst), "v"(e) : "memory");
  };

  if (v < 4) store_h(hold_s, 0u, 0u);   // phase 0: h0 -> slot 0, tag 0

  // ---- speculative tagged A-frag poll (16 active lanes: r=l&15<4, c=l>>4)
  auto acquire = [&](unsigned slotC, unsigned tagC,
                     u32x4& q0, u32x4& q1, u32x4& q2, u32x4& q3,
                     u32x4& q4, u32x4& q5, u32x4& q6, u32x4& q7) {
    const unsigned* ap = hb + slotC*SLOT_STRIDE
                       + ((unsigned)(b0g + (l & 15)) << 10)
                       + (unsigned)(v*128 + ((l >> 4) << 3));
    for (;;) {
      int ok;
      if ((l & 15) < 4) {
        POLL_BODY("sc0 sc1");
        ok = (dec_tag(q0) == tagC) & (dec_tag(q1) == tagC) &
             (dec_tag(q2) == tagC) & (dec_tag(q3) == tagC) &
             (dec_tag(q4) == tagC) & (dec_tag(q5) == tagC) &
             (dec_tag(q6) == tagC) & (dec_tag(q7) == tagC);
      } else ok = 1;
      if (__all(ok)) break;
      __builtin_amdgcn_s_sleep(1);
    }
  };

  // ---- iin partial MFMA (x, Win plain cached loads; k-slice 64 per wave)
  auto iin_partials = [&](int tt, f32x4 ax[4]) {
    const int r = l & 15, c = (l >> 4) << 3;
    const float* xp = x + ((size_t)(b0g + (r & 3))*S_DIM + tt)*IN_DIM + v*64 + c;
    f32x4 xq0 = *(const f32x4*)xp,        xq1 = *(const f32x4*)(xp + 4);
    f32x4 xq2 = *(const f32x4*)(xp + 32), xq3 = *(const f32x4*)(xp + 36);
#pragma unroll
    for (int i2 = 0; i2 < 2; ++i2) {
      s16x8 xh, xl;
      split_bf16(i2 ? xq2 : xq0, i2 ? xq3 : xq1, &xh, &xl);
#pragma unroll
      for (int nt = 0; nt < 4; ++nt) {
        const float* wp = Wiw + (size_t)(jw0 + nt*16 + (l & 15))*IN_DIM + v*64 + i2*32 + c;
        s16x8 wh, wl;
        split_bf16(*(const f32x4*)wp, *(const f32x4*)(wp + 4), &wh, &wl);
        ax[nt] = MFMA16(xh, wh, ax[nt], 0,0,0);
        ax[nt] = MFMA16(xl, wh, ax[nt], 0,0,0);
        ax[nt] = MFMA16(xh, wl, ax[nt], 0,0,0);
      }
    }
  };

  // ---- Wout B-frags on demand (16 oc per WG; all 16 cols real)
  auto load_wout = [&](s16x8 woY[4], s16x8 wlY[4]) {
#pragma unroll
    for (int i = 0; i < 4; ++i) {
      const int k0 = v*128 + i*32 + ((l >> 4) << 3);
      const size_t go = (size_t)(w*16 + (l & 15))*H_DIM + k0;
      split_bf16(*(const f32x4*)(Wow + go), *(const f32x4*)(Wow + go + 4),
                 &woY[i], &wlY[i]);
    }
  };

  // ---- pre-loop: iin(0) -> iin4 register (threads of waves 0..3)
  float iin4 = 0.f, iin_nx = 0.f;
  {
    f32x4 ax[4] = {{0,0,0,0},{0,0,0,0},{0,0,0,0},{0,0,0,0}};
    iin_partials(0, ax);
    if (l < 16) {
#pragma unroll
      for (int nt = 0; nt < 4; ++nt)
#pragma unroll
        for (int q = 0; q < 4; ++q) scx[v][q][nt*16 + l] = ax[nt][q];
    }
    __syncthreads();
    if (v < 4) {
      float s = wib_s;
#pragma unroll
      for (int kp = 0; kp < 8; ++kp) s += scx[kp][v][l];
      iin4 = s;
    }
    __syncthreads();
  }

  unsigned p = 1;
#pragma unroll 1
  for (int t = 0; t < S_DIM; ++t) {
#pragma unroll 1
    for (int u = 0; u < 6; ++u, ++p) {
      const unsigned slotC = (p-1) & 1, tagC = (p-1) & 0xFFFu;
      const unsigned slotP = p & 1,     tagP = p & 0xFFFu;
      const bool doY = (u == 0);
      const bool doX = (u == 3) && (t + 1 < S_DIM);

      s16x8 woY[4], wlY[4];
      if (doY) load_wout(woY, wlY);   // cached; overlaps the poll below

      u32x4 q0,q1,q2,q3,q4,q5,q6,q7;
      acquire(slotC, tagC, q0,q1,q2,q3,q4,q5,q6,q7);

      // ---- MFMA: 3-split bf16 (hh + lh + hl), B from registers
      f32x4 acc[4] = {{0,0,0,0},{0,0,0,0},{0,0,0,0},{0,0,0,0}};
      f32x4 accy = {0.f,0.f,0.f,0.f};
#pragma unroll
      for (int i = 0; i < 4; ++i) {
        u32x4 qa = (i==0) ? q0 : (i==1) ? q2 : (i==2) ? q4 : q6;
        u32x4 qb = (i==0) ? q1 : (i==1) ? q3 : (i==2) ? q5 : q7;
        s16x8 ah = pack_hi(qa, qb), al = pack_lo(qa, qb);
#pragma unroll
        for (int nt = 0; nt < 4; ++nt) {
          acc[nt] = MFMA16(ah, wbh[i][nt], acc[nt], 0,0,0);
          acc[nt] = MFMA16(al, wbh[i][nt], acc[nt], 0,0,0);
          acc[nt] = MFMA16(ah, wbl[i][nt], acc[nt], 0,0,0);
        }
        if (doY) {
          accy = MFMA16(ah, woY[i], accy, 0,0,0);
          accy = MFMA16(al, woY[i], accy, 0,0,0);
          accy = MFMA16(ah, wlY[i], accy, 0,0,0);
        }
      }
      f32x4 ax[4] = {{0,0,0,0},{0,0,0,0},{0,0,0,0},{0,0,0,0}};
      if (doX) iin_partials(t + 1, ax);

      // ---- partials -> LDS scratch (D rows 0..3 = batches, on lanes 0..15)
      if (l < 16) {
#pragma unroll
        for (int nt = 0; nt < 4; ++nt)
#pragma unroll
          for (int q = 0; q < 4; ++q) sch[slotP][v][q][nt*16 + l] = acc[nt][q];
        if (doX) {
#pragma unroll
          for (int nt = 0; nt < 4; ++nt)
#pragma unroll
            for (int q = 0; q < 4; ++q) scx[v][q][nt*16 + l] = ax[nt][q];
        }
        if (doY) {
#pragma unroll
          for (int q = 0; q < 4; ++q) scy[v][q][l] = accy[q];
        }
      }
      __syncthreads();

      // ---- distributed epilogue: wave v<4 owns batch v (64 lanes = 64 j)
      if (v < 4) {
        float ir = 0.f;
#pragma unroll
        for (int kp = 0; kp < 8; ++kp) ir += sch[slotP][kp][v][l];
        const float z  = (ir - mu_s) * sgi_s;
        const float f  = 1.0f / (1.0f + __expf(-z));
        const float dh = -al_s*hold_s + be_s*f*(iin4 + ir);
        const float hn = hold_s + tsc*dh*ti_s;
        hold_s = hn;
        store_h(hn, slotP, tagP);
        if (doX) {
          float s = wib_s;
#pragma unroll
          for (int kp = 0; kp < 8; ++kp) s += scx[kp][v][l];
          iin_nx = s;
        }
        if (u == 5) {
          if (t + 1 < S_DIM) {
            tsc = tspan[(size_t)gb_e*S_DIM + t + 1] * (1.0f/6.0f);
            iin4 = iin_nx;
          } else {
            out[OUT_Y_TOTAL + ((size_t)gb_e << 10) + gj] = hn;
          }
        }
      } else if (v == 4 && doY && t > 0) {
        // y(t-1) reduce + store: lane -> (b = l>>4, oc = l&15)
        const int b = l >> 4, oc = l & 15;
        float s = Wob[w*16 + oc];
#pragma unroll
        for (int kp = 0; kp < 8; ++kp) s += scy[kp][b][oc];
        out[((size_t)(b0g + b)*S_DIM + (t-1))*OUT_DIM + w*16 + oc] = s;
      }
    }
  }

  // ---- tail: y(S-1) from final h (phase 1536)
  {
    const unsigned slotC = (p-1) & 1, tagC = (p-1) & 0xFFFu;
    s16x8 woY[4], wlY[4];
    load_wout(woY, wlY);
    u32x4 q0,q1,q2,q3,q4,q5,q6,q7;
    acquire(slotC, tagC, q0,q1,q2,q3,q4,q5,q6,q7);
    f32x4 accy = {0.f,0.f,0.f,0.f};
#pragma unroll
    for (int i = 0; i < 4; ++i) {
      u32x4 qa = (i==0) ? q0 : (i==1) ? q2 : (i==2) ? q4 : q6;
      u32x4 qb = (i==0) ? q1 : (i==1) ? q3 : (i==2) ? q5 : q7;
      s16x8 ah = pack_hi(qa, qb), al = pack_lo(qa, qb);
      accy = MFMA16(ah, woY[i], accy, 0,0,0);
      accy = MFMA16(al, woY[i], accy, 0,0,0);
      accy = MFMA16(ah, wlY[i], accy, 0,0,0);
    }
    if (l < 16) {
#pragma unroll
      for (int q = 0; q < 4; ++q) scy[v][q][l] = accy[q];
    }
    __syncthreads();
    if (v == 4) {
      const int b = l >> 4, oc = l & 15;
      float s = Wob[w*16 + oc];
#pragma unroll
      for (int kp = 0; kp < 8; ++kp) s += scy[kp][b][oc];
      out[((size_t)(b0g + b)*S_DIM + (S_DIM-1))*OUT_DIM + w*16 + oc] = s;
    }
  }
}

extern "C" void kernel_launch(void* const* d_in, const int* in_sizes, int n_in,
                              void* d_out, int out_size, void* d_ws, size_t ws_size,
                              hipStream_t stream) {
  const float* x    = (const float*)d_in[0];
  const float* h0   = (const float*)d_in[1];
  const float* ts   = (const float*)d_in[2];
  const float* tau  = (const float*)d_in[3];
  const float* Wiw  = (const float*)d_in[4];
  const float* Wib  = (const float*)d_in[5];
  const float* Wrw  = (const float*)d_in[6];
  const float* msk  = (const float*)d_in[7];
  const float* Wow  = (const float*)d_in[8];
  const float* Wob  = (const float*)d_in[9];
  const float* alp  = (const float*)d_in[10];
  const float* bet  = (const float*)d_in[11];
  const float* mu   = (const float*)d_in[12];
  const float* sg   = (const float*)d_in[13];
  float* out = (float*)d_out;
  unsigned* hb = (unsigned*)d_ws;   // 2 slots x 256KB tagged h exchange

  // poison all tags (decode 4095 = never valid) -> replay-deterministic
  hipMemsetAsync(hb, 0xFF, 2*SLOT_STRIDE*sizeof(unsigned), stream);

  void* args[] = { (void*)&x, (void*)&h0, (void*)&ts, (void*)&tau,
                   (void*)&Wiw, (void*)&Wib, (void*)&Wrw, (void*)&msk,
                   (void*)&Wow, (void*)&Wob, (void*)&alp, (void*)&bet,
                   (void*)&mu, (void*)&sg, (void*)&out, (void*)&hb };
  hipLaunchCooperativeKernel((const void*)ltc_kernel, dim3(NWG), dim3(NTHREADS),
                             args, 0, stream);
}

// Round 11
// 8926.388 us; speedup vs baseline: 1.1332x; 1.0739x over previous
//
#include <hip/hip_runtime.h>

#define IN_DIM   512
#define H_DIM    1024
#define OUT_DIM  256
#define B_DIM    64
#define S_DIM    256
#define EPS_F    1e-8f

#define BPG      4      // batches per group
#define JPW      64     // j-columns per WG
#define NTHREADS 512
#define NWG      256    // one WG per CU (LDS pad)
#define SLOT_STRIDE 65536   // u32 elements per exchange slot

#define OUT_Y_TOTAL ((size_t)B_DIM*S_DIM*OUT_DIM)

typedef float    f32x4 __attribute__((ext_vector_type(4)));
typedef unsigned u32x4 __attribute__((ext_vector_type(4)));
typedef short    s16x8 __attribute__((ext_vector_type(8)));

#define MFMA16 __builtin_amdgcn_mfma_f32_16x16x32_bf16

union B8 { unsigned u[4]; s16x8 v; };

// split f32 -> (bf16 hi, bf16 lo) by truncation; hi+lo reconstructs ~2^-16 rel.
__device__ __forceinline__ void split_bf16(f32x4 f0, f32x4 f1, s16x8* hi, s16x8* lo) {
  B8 H, L;
  float fv[8];
#pragma unroll
  for (int e = 0; e < 4; ++e) { fv[e] = f0[e]; fv[e+4] = f1[e]; }
#pragma unroll
  for (int d = 0; d < 4; ++d) {
    unsigned u0 = __float_as_uint(fv[2*d]);
    unsigned u1 = __float_as_uint(fv[2*d+1]);
    unsigned t0 = u0 & 0xffff0000u, t1 = u1 & 0xffff0000u;
    H.u[d] = (u0 >> 16) | t1;
    L.u[d] = ((__float_as_uint(fv[2*d]   - __uint_as_float(t0))) >> 16)
           | ((__float_as_uint(fv[2*d+1] - __uint_as_float(t1))) & 0xffff0000u);
  }
  *hi = H.v; *lo = L.v;
}

// bf16-hi-only split (for W_out: y does not feed the recurrence)
__device__ __forceinline__ s16x8 split_hi_only(f32x4 f0, f32x4 f1) {
  B8 H;
#pragma unroll
  for (int d = 0; d < 4; ++d) {
    unsigned u0 = __float_as_uint(d < 2 ? f0[2*d]   : f1[2*d-4]);
    unsigned u1 = __float_as_uint(d < 2 ? f0[2*d+1] : f1[2*d-3]);
    H.u[d] = (u0 >> 16) | (u1 & 0xffff0000u);
  }
  return H.v;
}

// 12-bit phase tag spread 3 bits per word of each 16B granule (R7-proven).
__device__ __forceinline__ unsigned dec_tag(u32x4 q) {
  return (q.x & 7u) | ((q.y & 7u) << 3) | ((q.z & 7u) << 6) | ((q.w & 7u) << 9);
}
__device__ __forceinline__ s16x8 pack_hi(u32x4 a, u32x4 b) {
  B8 t;
  t.u[0] = (a.y & 0xFFFF0000u) | (a.x >> 16);
  t.u[1] = (a.w & 0xFFFF0000u) | (a.z >> 16);
  t.u[2] = (b.y & 0xFFFF0000u) | (b.x >> 16);
  t.u[3] = (b.w & 0xFFFF0000u) | (b.z >> 16);
  return t.v;
}
__device__ __forceinline__ s16x8 pack_lo(u32x4 a, u32x4 b) {
  B8 t;   // strip 3 stolen tag bits from every residual word
  t.u[0] = ((a.y & 0xFFF8u) << 16) | (a.x & 0xFFF8u);
  t.u[1] = ((a.w & 0xFFF8u) << 16) | (a.z & 0xFFF8u);
  t.u[2] = ((b.y & 0xFFF8u) << 16) | (b.x & 0xFFF8u);
  t.u[3] = ((b.w & 0xFFF8u) << 16) | (b.z & 0xFFF8u);
  return t.v;
}

#define POLL_BODY(FLAGS)                                                      \
  asm volatile(                                                               \
    "global_load_dwordx4 %0, %8, off " FLAGS "\n\t"                           \
    "global_load_dwordx4 %1, %8, off offset:16 " FLAGS "\n\t"                 \
    "global_load_dwordx4 %2, %8, off offset:128 " FLAGS "\n\t"                \
    "global_load_dwordx4 %3, %8, off offset:144 " FLAGS "\n\t"                \
    "global_load_dwordx4 %4, %8, off offset:256 " FLAGS "\n\t"                \
    "global_load_dwordx4 %5, %8, off offset:272 " FLAGS "\n\t"                \
    "global_load_dwordx4 %6, %8, off offset:384 " FLAGS "\n\t"                \
    "global_load_dwordx4 %7, %8, off offset:400 " FLAGS "\n\t"                \
    "s_waitcnt vmcnt(0)"                                                      \
    : "=&v"(q0), "=&v"(q1), "=&v"(q2), "=&v"(q3),                             \
      "=&v"(q4), "=&v"(q5), "=&v"(q6), "=&v"(q7)                              \
    : "v"(ap) : "memory")

__global__ void __launch_bounds__(NTHREADS, 1)
ltc_kernel(const float* __restrict__ x, const float* __restrict__ h0,
           const float* __restrict__ tspan, const float* __restrict__ tau,
           const float* __restrict__ Wiw, const float* __restrict__ Wib,
           const float* __restrict__ Wrw, const float* __restrict__ wmask,
           const float* __restrict__ Wow, const float* __restrict__ Wob,
           const float* __restrict__ alpha_p, const float* __restrict__ beta_p,
           const float* __restrict__ mu_p, const float* __restrict__ sigma_p,
           float* __restrict__ out, unsigned* __restrict__ hb)
{
  __shared__ float sch[2][8][4][68];   // [slot][kp][b][j] h partials (17408 B)
  __shared__ float scx[8][4][68];      // iin partials (8704 B)
  __shared__ float scy[8][4][20];      // y partials (2560 B)
  __shared__ char lds_pad[57344];      // 1 WG/CU (perf only; no correctness dep)

  const int tid = threadIdx.x;
  ((volatile char*)lds_pad)[tid] = 0;

  const int wg  = blockIdx.x;
  const int g   = wg >> 4;          // group: 4 batches
  const int w   = wg & 15;          // j-slice (64 cols) within group
  const int b0g = g * BPG;
  const int jw0 = w * JPW;
  const int l   = tid & 63;
  const int v   = tid >> 6;         // wave id = K-part (k in [128v,128v+128))
  const int vb  = v & 3;
  const int gb_e = b0g + vb;        // epilogue batch (waves 0..3 only)
  const int gj  = jw0 + l;          // epilogue column (1/lane)

  // ---- W_rec B-frags (masked, split bf16) -> registers, permanent (128 VGPR)
  s16x8 wbh[4][4], wbl[4][4];
#pragma unroll
  for (int i = 0; i < 4; ++i) {
    const int k0 = v*128 + i*32 + ((l >> 4) << 3);
#pragma unroll
    for (int nt = 0; nt < 4; ++nt) {
      const size_t go = (size_t)(jw0 + nt*16 + (l & 15))*H_DIM + k0;
      f32x4 w0 = *(const f32x4*)(Wrw + go)     * *(const f32x4*)(wmask + go);
      f32x4 w1 = *(const f32x4*)(Wrw + go + 4) * *(const f32x4*)(wmask + go + 4);
      split_bf16(w0, w1, &wbh[i][nt], &wbl[i][nt]);
    }
  }

  // ---- per-thread epilogue state: (b = v, j = lane), scalar
  const float mu_s  = mu_p[gj];
  const float sgi_s = 1.0f / (sigma_p[gj] + EPS_F);
  const float al_s  = alpha_p[gj];
  const float be_s  = beta_p[gj];
  const float ti_s  = 1.0f / tau[gj];
  const float wib_s = Wib[gj];
  float hold_s = h0[((size_t)gb_e << 10) + gj];
  float tsc = tspan[(size_t)gb_e*S_DIM] * (1.0f/6.0f);

  // ---- publish one h element (tag piece by j%4; R7 encoding)
  auto store_h = [&](float hn, unsigned slot, unsigned tag) {
    unsigned uh = __float_as_uint(hn) & 0xFFFF0000u;
    float r = hn - __uint_as_float(uh);
    unsigned e = (uh | (__float_as_uint(r) >> 16)) & ~7u;
    e |= (tag >> (3*(l & 3))) & 7u;
    unsigned* dst = hb + slot*SLOT_STRIDE + ((unsigned)gb_e << 10) + (unsigned)gj;
    asm volatile("global_store_dword %0, %1, off sc0 sc1"
                 :: "v"(dst), "v"(e) : "memory");
  };

  if (v < 4) store_h(hold_s, 0u, 0u);   // phase 0: h0 -> slot 0, tag 0

  // ---- speculative tagged A-frag poll (active lanes: l&15 < 4)
  auto acquire = [&](unsigned slotC, unsigned tagC,
                     u32x4& q0, u32x4& q1, u32x4& q2, u32x4& q3,
                     u32x4& q4, u32x4& q5, u32x4& q6, u32x4& q7) {
    const unsigned* ap = hb + slotC*SLOT_STRIDE
                       + ((unsigned)(b0g + (l & 15)) << 10)
                       + (unsigned)(v*128 + ((l >> 4) << 3));
    for (;;) {
      int ok;
      if ((l & 15) < 4) {
        POLL_BODY("sc0 sc1");
        ok = (dec_tag(q0) == tagC) & (dec_tag(q1) == tagC) &
             (dec_tag(q2) == tagC) & (dec_tag(q3) == tagC) &
             (dec_tag(q4) == tagC) & (dec_tag(q5) == tagC) &
             (dec_tag(q6) == tagC) & (dec_tag(q7) == tagC);
      } else ok = 1;
      if (__all(ok)) break;
      __builtin_amdgcn_s_sleep(1);
    }
  };

  // ---- iin partial MFMA (x, Win plain cached loads; k-slice 64 per wave)
  auto iin_partials = [&](int tt, f32x4 ax[4]) {
    const int r = l & 15, c = (l >> 4) << 3;
    const float* xp = x + ((size_t)(b0g + (r & 3))*S_DIM + tt)*IN_DIM + v*64 + c;
    f32x4 xq0 = *(const f32x4*)xp,        xq1 = *(const f32x4*)(xp + 4);
    f32x4 xq2 = *(const f32x4*)(xp + 32), xq3 = *(const f32x4*)(xp + 36);
#pragma unroll
    for (int i2 = 0; i2 < 2; ++i2) {
      s16x8 xh, xl;
      split_bf16(i2 ? xq2 : xq0, i2 ? xq3 : xq1, &xh, &xl);
#pragma unroll
      for (int nt = 0; nt < 4; ++nt) {
        const float* wp = Wiw + (size_t)(jw0 + nt*16 + (l & 15))*IN_DIM + v*64 + i2*32 + c;
        s16x8 wh, wl;
        split_bf16(*(const f32x4*)wp, *(const f32x4*)(wp + 4), &wh, &wl);
        ax[nt] = MFMA16(xh, wh, ax[nt], 0,0,0);
        ax[nt] = MFMA16(xl, wh, ax[nt], 0,0,0);
        ax[nt] = MFMA16(xh, wl, ax[nt], 0,0,0);
      }
    }
  };

  // ---- Wout B-frags on demand, HI ONLY (y doesn't feed the recurrence)
  auto load_wout = [&](s16x8 woY[4]) {
#pragma unroll
    for (int i = 0; i < 4; ++i) {
      const int k0 = v*128 + i*32 + ((l >> 4) << 3);
      const size_t go = (size_t)(w*16 + (l & 15))*H_DIM + k0;
      woY[i] = split_hi_only(*(const f32x4*)(Wow + go), *(const f32x4*)(Wow + go + 4));
    }
  };

  // ---- pre-loop: iin(0) -> iin4 register (threads of waves 0..3)
  float iin4 = 0.f, iin_nx = 0.f;
  {
    f32x4 ax[4] = {{0,0,0,0},{0,0,0,0},{0,0,0,0},{0,0,0,0}};
    iin_partials(0, ax);
    if (l < 16) {
#pragma unroll
      for (int nt = 0; nt < 4; ++nt)
#pragma unroll
        for (int q = 0; q < 4; ++q) scx[v][q][nt*16 + l] = ax[nt][q];
    }
    __syncthreads();
    if (v < 4) {
      float s = wib_s;
#pragma unroll
      for (int kp = 0; kp < 8; ++kp) s += scx[kp][v][l];
      iin4 = s;
    }
    __syncthreads();
  }

  unsigned p = 1;
#pragma unroll 1
  for (int t = 0; t < S_DIM; ++t) {
#pragma unroll 1
    for (int u = 0; u < 6; ++u, ++p) {
      const unsigned slotC = (p-1) & 1, tagC = (p-1) & 0xFFFu;
      const unsigned slotP = p & 1,     tagP = p & 0xFFFu;
      const bool doY = (u == 0);
      const bool doX = (u == 3) && (t + 1 < S_DIM);

      s16x8 woY[4];
      if (doY) load_wout(woY);      // cached; overlaps the poll below

      u32x4 q0,q1,q2,q3,q4,q5,q6,q7;
      acquire(slotC, tagC, q0,q1,q2,q3,q4,q5,q6,q7);

      // ---- MFMA: 3-split bf16 (hh + lh + hl), B from registers
      f32x4 acc[4] = {{0,0,0,0},{0,0,0,0},{0,0,0,0},{0,0,0,0}};
      f32x4 accy = {0.f,0.f,0.f,0.f};
#pragma unroll
      for (int i = 0; i < 4; ++i) {
        u32x4 qa = (i==0) ? q0 : (i==1) ? q2 : (i==2) ? q4 : q6;
        u32x4 qb = (i==0) ? q1 : (i==1) ? q3 : (i==2) ? q5 : q7;
        s16x8 ah = pack_hi(qa, qb), al = pack_lo(qa, qb);
#pragma unroll
        for (int nt = 0; nt < 4; ++nt) {
          acc[nt] = MFMA16(ah, wbh[i][nt], acc[nt], 0,0,0);
          acc[nt] = MFMA16(al, wbh[i][nt], acc[nt], 0,0,0);
          acc[nt] = MFMA16(ah, wbl[i][nt], acc[nt], 0,0,0);
        }
        if (doY) {
          accy = MFMA16(ah, woY[i], accy, 0,0,0);
          accy = MFMA16(al, woY[i], accy, 0,0,0);
        }
      }
      f32x4 ax[4] = {{0,0,0,0},{0,0,0,0},{0,0,0,0},{0,0,0,0}};
      if (doX) iin_partials(t + 1, ax);

      // ---- partials -> LDS scratch (D rows 0..3 = batches, on lanes 0..15)
      if (l < 16) {
#pragma unroll
        for (int nt = 0; nt < 4; ++nt)
#pragma unroll
          for (int q = 0; q < 4; ++q) sch[slotP][v][q][nt*16 + l] = acc[nt][q];
        if (doX) {
#pragma unroll
          for (int nt = 0; nt < 4; ++nt)
#pragma unroll
            for (int q = 0; q < 4; ++q) scx[v][q][nt*16 + l] = ax[nt][q];
        }
        if (doY) {
#pragma unroll
          for (int q = 0; q < 4; ++q) scy[v][q][l] = accy[q];
        }
      }
      __syncthreads();

      // ---- distributed epilogue: wave v<4 owns batch v (64 lanes = 64 j)
      if (v < 4) {
        float ir = 0.f;
#pragma unroll
        for (int kp = 0; kp < 8; ++kp) ir += sch[slotP][kp][v][l];
        const float z  = (ir - mu_s) * sgi_s;
        const float f  = 1.0f / (1.0f + __expf(-z));
        const float dh = -al_s*hold_s + be_s*f*(iin4 + ir);
        const float hn = hold_s + tsc*dh*ti_s;
        hold_s = hn;
        store_h(hn, slotP, tagP);
        if (doX) {
          float s = wib_s;
#pragma unroll
          for (int kp = 0; kp < 8; ++kp) s += scx[kp][v][l];
          iin_nx = s;
        }
        if (u == 5) {
          if (t + 1 < S_DIM) {
            tsc = tspan[(size_t)gb_e*S_DIM + t + 1] * (1.0f/6.0f);
            iin4 = iin_nx;
          } else {
            out[OUT_Y_TOTAL + ((size_t)gb_e << 10) + gj] = hn;
          }
        }
      } else if (v == 4 && doY && t > 0) {
        // y(t-1) reduce + store: lane -> (b = l>>4, oc = l&15)
        const int b = l >> 4, oc = l & 15;
        float s = Wob[w*16 + oc];
#pragma unroll
        for (int kp = 0; kp < 8; ++kp) s += scy[kp][b][oc];
        out[((size_t)(b0g + b)*S_DIM + (t-1))*OUT_DIM + w*16 + oc] = s;
      }
    }
  }

  // ---- tail: y(S-1) from final h (phase 1536)
  {
    const unsigned slotC = (p-1) & 1, tagC = (p-1) & 0xFFFu;
    s16x8 woY[4];
    load_wout(woY);
    u32x4 q0,q1,q2,q3,q4,q5,q6,q7;
    acquire(slotC, tagC, q0,q1,q2,q3,q4,q5,q6,q7);
    f32x4 accy = {0.f,0.f,0.f,0.f};
#pragma unroll
    for (int i = 0; i < 4; ++i) {
      u32x4 qa = (i==0) ? q0 : (i==1) ? q2 : (i==2) ? q4 : q6;
      u32x4 qb = (i==0) ? q1 : (i==1) ? q3 : (i==2) ? q5 : q7;
      s16x8 ah = pack_hi(qa, qb), al = pack_lo(qa, qb);
      accy = MFMA16(ah, woY[i], accy, 0,0,0);
      accy = MFMA16(al, woY[i], accy, 0,0,0);
    }
    if (l < 16) {
#pragma unroll
      for (int q = 0; q < 4; ++q) scy[v][q][l] = accy[q];
    }
    __syncthreads();
    if (v == 4) {
      const int b = l >> 4, oc = l & 15;
      float s = Wob[w*16 + oc];
#pragma unroll
      for (int kp = 0; kp < 8; ++kp) s += scy[kp][b][oc];
      out[((size_t)(b0g + b)*S_DIM + (S_DIM-1))*OUT_DIM + w*16 + oc] = s;
    }
  }
}

extern "C" void kernel_launch(void* const* d_in, const int* in_sizes, int n_in,
                              void* d_out, int out_size, void* d_ws, size_t ws_size,
                              hipStream_t stream) {
  const float* x    = (const float*)d_in[0];
  const float* h0   = (const float*)d_in[1];
  const float* ts   = (const float*)d_in[2];
  const float* tau  = (const float*)d_in[3];
  const float* Wiw  = (const float*)d_in[4];
  const float* Wib  = (const float*)d_in[5];
  const float* Wrw  = (const float*)d_in[6];
  const float* msk  = (const float*)d_in[7];
  const float* Wow  = (const float*)d_in[8];
  const float* Wob  = (const float*)d_in[9];
  const float* alp  = (const float*)d_in[10];
  const float* bet  = (const float*)d_in[11];
  const float* mu   = (const float*)d_in[12];
  const float* sg   = (const float*)d_in[13];
  float* out = (float*)d_out;
  unsigned* hb = (unsigned*)d_ws;   // 2 slots x 256KB tagged h exchange

  // poison all tags (decode 4095 = never valid) -> replay-deterministic
  hipMemsetAsync(hb, 0xFF, 2*SLOT_STRIDE*sizeof(unsigned), stream);

  void* args[] = { (void*)&x, (void*)&h0, (void*)&ts, (void*)&tau,
                   (void*)&Wiw, (void*)&Wib, (void*)&Wrw, (void*)&msk,
                   (void*)&Wow, (void*)&Wob, (void*)&alp, (void*)&bet,
                   (void*)&mu, (void*)&sg, (void*)&out, (void*)&hb };
  hipLaunchCooperativeKernel((const void*)ltc_kernel, dim3(NWG), dim3(NTHREADS),
                             args, 0, stream);
}

// Round 12
// 5573.995 us; speedup vs baseline: 1.8147x; 1.6014x over previous
//
#include <hip/hip_runtime.h>

#define IN_DIM   512
#define H_DIM    1024
#define OUT_DIM  256
#define B_DIM    64
#define S_DIM    256
#define EPS_F    1e-8f

#define BPG      4      // batches per group
#define JPW      64     // j-columns per WG
#define NTHREADS 512
#define NWG      256    // one WG per CU (LDS pad)
#define SLOT_STRIDE 65536   // u32 elements per exchange slot

#define OUT_Y_TOTAL ((size_t)B_DIM*S_DIM*OUT_DIM)

typedef float    f32x4 __attribute__((ext_vector_type(4)));
typedef unsigned u32x4 __attribute__((ext_vector_type(4)));
typedef short    s16x8 __attribute__((ext_vector_type(8)));

#define MFMA16 __builtin_amdgcn_mfma_f32_16x16x32_bf16

union B8 { unsigned u[4]; s16x8 v; };

// round-to-nearest bf16 pack of 8 floats (weights: rel err <= 2^-10)
__device__ __forceinline__ s16x8 round_bf16x8(f32x4 f0, f32x4 f1) {
  B8 H;
  float fv[8];
#pragma unroll
  for (int e = 0; e < 4; ++e) { fv[e] = f0[e]; fv[e+4] = f1[e]; }
#pragma unroll
  for (int d = 0; d < 4; ++d) {
    unsigned u0 = __float_as_uint(fv[2*d])   + 0x8000u;
    unsigned u1 = __float_as_uint(fv[2*d+1]) + 0x8000u;
    H.u[d] = (u0 >> 16) | (u1 & 0xFFFF0000u);
  }
  return H.v;
}

// split f32 -> (bf16 hi, bf16 lo) by truncation (for A-side: x, h exchange)
__device__ __forceinline__ void split_bf16(f32x4 f0, f32x4 f1, s16x8* hi, s16x8* lo) {
  B8 H, L;
  float fv[8];
#pragma unroll
  for (int e = 0; e < 4; ++e) { fv[e] = f0[e]; fv[e+4] = f1[e]; }
#pragma unroll
  for (int d = 0; d < 4; ++d) {
    unsigned u0 = __float_as_uint(fv[2*d]);
    unsigned u1 = __float_as_uint(fv[2*d+1]);
    unsigned t0 = u0 & 0xffff0000u, t1 = u1 & 0xffff0000u;
    H.u[d] = (u0 >> 16) | t1;
    L.u[d] = ((__float_as_uint(fv[2*d]   - __uint_as_float(t0))) >> 16)
           | ((__float_as_uint(fv[2*d+1] - __uint_as_float(t1))) & 0xffff0000u);
  }
  *hi = H.v; *lo = L.v;
}

// 12-bit phase tag spread 3 bits per word of each 16B granule (R7-proven).
__device__ __forceinline__ unsigned dec_tag(u32x4 q) {
  return (q.x & 7u) | ((q.y & 7u) << 3) | ((q.z & 7u) << 6) | ((q.w & 7u) << 9);
}
__device__ __forceinline__ s16x8 pack_hi(u32x4 a, u32x4 b) {
  B8 t;
  t.u[0] = (a.y & 0xFFFF0000u) | (a.x >> 16);
  t.u[1] = (a.w & 0xFFFF0000u) | (a.z >> 16);
  t.u[2] = (b.y & 0xFFFF0000u) | (b.x >> 16);
  t.u[3] = (b.w & 0xFFFF0000u) | (b.z >> 16);
  return t.v;
}
__device__ __forceinline__ s16x8 pack_lo(u32x4 a, u32x4 b) {
  B8 t;   // strip 3 stolen tag bits from every residual word
  t.u[0] = ((a.y & 0xFFF8u) << 16) | (a.x & 0xFFF8u);
  t.u[1] = ((a.w & 0xFFF8u) << 16) | (a.z & 0xFFF8u);
  t.u[2] = ((b.y & 0xFFF8u) << 16) | (b.x & 0xFFF8u);
  t.u[3] = ((b.w & 0xFFF8u) << 16) | (b.z & 0xFFF8u);
  return t.v;
}

#define POLL_BODY(FLAGS)                                                      \
  asm volatile(                                                               \
    "global_load_dwordx4 %0, %8, off " FLAGS "\n\t"                           \
    "global_load_dwordx4 %1, %8, off offset:16 " FLAGS "\n\t"                 \
    "global_load_dwordx4 %2, %8, off offset:128 " FLAGS "\n\t"                \
    "global_load_dwordx4 %3, %8, off offset:144 " FLAGS "\n\t"                \
    "global_load_dwordx4 %4, %8, off offset:256 " FLAGS "\n\t"                \
    "global_load_dwordx4 %5, %8, off offset:272 " FLAGS "\n\t"                \
    "global_load_dwordx4 %6, %8, off offset:384 " FLAGS "\n\t"                \
    "global_load_dwordx4 %7, %8, off offset:400 " FLAGS "\n\t"                \
    "s_waitcnt vmcnt(0)"                                                      \
    : "=&v"(q0), "=&v"(q1), "=&v"(q2), "=&v"(q3),                             \
      "=&v"(q4), "=&v"(q5), "=&v"(q6), "=&v"(q7)                              \
    : "v"(ap) : "memory")

__global__ void __launch_bounds__(NTHREADS)
ltc_kernel(const float* __restrict__ x, const float* __restrict__ h0,
           const float* __restrict__ tspan, const float* __restrict__ tau,
           const float* __restrict__ Wiw, const float* __restrict__ Wib,
           const float* __restrict__ Wrw, const float* __restrict__ wmask,
           const float* __restrict__ Wow, const float* __restrict__ Wob,
           const float* __restrict__ alpha_p, const float* __restrict__ beta_p,
           const float* __restrict__ mu_p, const float* __restrict__ sigma_p,
           float* __restrict__ out, unsigned* __restrict__ hb)
{
  __shared__ float sch[2][8][4][68];   // [slot][kp][b][j] h partials (17408 B)
  __shared__ float scx[8][4][68];      // iin partials (8704 B)
  __shared__ float scy[8][4][20];      // y partials (2560 B)
  __shared__ char lds_pad[57344];      // 1 WG/CU (perf only; no correctness dep)

  const int tid = threadIdx.x;
  ((volatile char*)lds_pad)[tid] = 0;

  const int wg  = blockIdx.x;
  const int g   = wg >> 4;          // group: 4 batches (16 groups)
  const int w   = wg & 15;          // j-slice (64 cols) within group
  const int b0g = g * BPG;
  const int jw0 = w * JPW;
  const int l   = tid & 63;
  const int v   = tid >> 6;         // wave id = K-part (k in [128v,128v+128))
  const int vb  = v & 3;
  const int gb_e = b0g + vb;        // epilogue batch (waves 0..3 only)
  const int gj  = jw0 + l;          // epilogue column (1/lane)

  // ---- W_rec B-frags (masked, ROUNDED bf16-hi only) -> registers (64 VGPR)
  s16x8 wbh[4][4];
#pragma unroll
  for (int i = 0; i < 4; ++i) {
    const int k0 = v*128 + i*32 + ((l >> 4) << 3);
#pragma unroll
    for (int nt = 0; nt < 4; ++nt) {
      const size_t go = (size_t)(jw0 + nt*16 + (l & 15))*H_DIM + k0;
      f32x4 w0 = *(const f32x4*)(Wrw + go)     * *(const f32x4*)(wmask + go);
      f32x4 w1 = *(const f32x4*)(Wrw + go + 4) * *(const f32x4*)(wmask + go + 4);
      wbh[i][nt] = round_bf16x8(w0, w1);
    }
  }

  // ---- per-thread epilogue state: (b = vb, j = lane), scalar
  const float mu_s  = mu_p[gj];
  const float sgi_s = 1.0f / (sigma_p[gj] + EPS_F);
  const float al_s  = alpha_p[gj];
  const float be_s  = beta_p[gj];
  const float ti_s  = 1.0f / tau[gj];
  const float wib_s = Wib[gj];
  float hold_s = h0[((size_t)gb_e << 10) + gj];
  float tsc = tspan[(size_t)gb_e*S_DIM] * (1.0f/6.0f);

  // ---- publish one h element (tag piece by j%4; R7 encoding)
  auto store_h = [&](float hn, unsigned slot, unsigned tag) {
    unsigned uh = __float_as_uint(hn) & 0xFFFF0000u;
    float r = hn - __uint_as_float(uh);
    unsigned e = (uh | (__float_as_uint(r) >> 16)) & ~7u;
    e |= (tag >> (3*(l & 3))) & 7u;
    unsigned* dst = hb + slot*SLOT_STRIDE + ((unsigned)gb_e << 10) + (unsigned)gj;
    asm volatile("global_store_dword %0, %1, off sc0 sc1"
                 :: "v"(dst), "v"(e) : "memory");
  };

  if (v < 4) store_h(hold_s, 0u, 0u);   // phase 0: h0 -> slot 0, tag 0

  // ---- speculative tagged A-frag poll (active lanes: l&15 < 4)
  auto acquire = [&](unsigned slotC, unsigned tagC,
                     u32x4& q0, u32x4& q1, u32x4& q2, u32x4& q3,
                     u32x4& q4, u32x4& q5, u32x4& q6, u32x4& q7) {
    const unsigned* ap = hb + slotC*SLOT_STRIDE
                       + ((unsigned)(b0g + (l & 15)) << 10)
                       + (unsigned)(v*128 + ((l >> 4) << 3));
    for (;;) {
      int ok;
      if ((l & 15) < 4) {
        POLL_BODY("sc0 sc1");
        ok = (dec_tag(q0) == tagC) & (dec_tag(q1) == tagC) &
             (dec_tag(q2) == tagC) & (dec_tag(q3) == tagC) &
             (dec_tag(q4) == tagC) & (dec_tag(q5) == tagC) &
             (dec_tag(q6) == tagC) & (dec_tag(q7) == tagC);
      } else ok = 1;
      if (__all(ok)) break;
      __builtin_amdgcn_s_sleep(1);
    }
  };

  // ---- iin partial MFMA (x split hi/lo; Win ROUNDED hi; 2 MFMAs per tile)
  auto iin_partials = [&](int tt, f32x4 ax[4]) {
    const int r = l & 15, c = (l >> 4) << 3;
    const float* xp = x + ((size_t)(b0g + (r & 3))*S_DIM + tt)*IN_DIM + v*64 + c;
    f32x4 xq0 = *(const f32x4*)xp,        xq1 = *(const f32x4*)(xp + 4);
    f32x4 xq2 = *(const f32x4*)(xp + 32), xq3 = *(const f32x4*)(xp + 36);
#pragma unroll
    for (int i2 = 0; i2 < 2; ++i2) {
      s16x8 xh, xl;
      split_bf16(i2 ? xq2 : xq0, i2 ? xq3 : xq1, &xh, &xl);
#pragma unroll
      for (int nt = 0; nt < 4; ++nt) {
        const float* wp = Wiw + (size_t)(jw0 + nt*16 + (l & 15))*IN_DIM + v*64 + i2*32 + c;
        s16x8 wh = round_bf16x8(*(const f32x4*)wp, *(const f32x4*)(wp + 4));
        ax[nt] = MFMA16(xh, wh, ax[nt], 0,0,0);
        ax[nt] = MFMA16(xl, wh, ax[nt], 0,0,0);
      }
    }
  };

  // ---- Wout B-frags on demand, ROUNDED hi only
  auto load_wout = [&](s16x8 woY[4]) {
#pragma unroll
    for (int i = 0; i < 4; ++i) {
      const int k0 = v*128 + i*32 + ((l >> 4) << 3);
      const size_t go = (size_t)(w*16 + (l & 15))*H_DIM + k0;
      woY[i] = round_bf16x8(*(const f32x4*)(Wow + go), *(const f32x4*)(Wow + go + 4));
    }
  };

  // ---- pre-loop: iin(0) -> iin4 register (threads of waves 0..3)
  float iin4 = 0.f, iin_nx = 0.f;
  {
    f32x4 ax[4] = {{0,0,0,0},{0,0,0,0},{0,0,0,0},{0,0,0,0}};
    iin_partials(0, ax);
    if (l < 16) {
#pragma unroll
      for (int nt = 0; nt < 4; ++nt)
#pragma unroll
        for (int q = 0; q < 4; ++q) scx[v][q][nt*16 + l] = ax[nt][q];
    }
    __syncthreads();
    if (v < 4) {
      float s = wib_s;
#pragma unroll
      for (int kp = 0; kp < 8; ++kp) s += scx[kp][vb][l];
      iin4 = s;
    }
    __syncthreads();
  }

  unsigned p = 1;
#pragma unroll 1
  for (int t = 0; t < S_DIM; ++t) {
#pragma unroll 1
    for (int u = 0; u < 6; ++u, ++p) {
      const unsigned slotC = (p-1) & 1, tagC = (p-1) & 0xFFFu;
      const unsigned slotP = p & 1,     tagP = p & 0xFFFu;
      const bool doY = (u == 0);
      const bool doX = (u == 3) && (t + 1 < S_DIM);

      s16x8 woY[4];
      if (doY) load_wout(woY);      // cached; overlaps the poll below

      u32x4 q0,q1,q2,q3,q4,q5,q6,q7;
      acquire(slotC, tagC, q0,q1,q2,q3,q4,q5,q6,q7);

      // ---- MFMA: 2-term (h_hi*W + h_lo*W), rounded-bf16 W from registers
      f32x4 acc[4] = {{0,0,0,0},{0,0,0,0},{0,0,0,0},{0,0,0,0}};
      f32x4 accy = {0.f,0.f,0.f,0.f};
#pragma unroll
      for (int i = 0; i < 4; ++i) {
        u32x4 qa = (i==0) ? q0 : (i==1) ? q2 : (i==2) ? q4 : q6;
        u32x4 qb = (i==0) ? q1 : (i==1) ? q3 : (i==2) ? q5 : q7;
        s16x8 ah = pack_hi(qa, qb), al = pack_lo(qa, qb);
#pragma unroll
        for (int nt = 0; nt < 4; ++nt) {
          acc[nt] = MFMA16(ah, wbh[i][nt], acc[nt], 0,0,0);
          acc[nt] = MFMA16(al, wbh[i][nt], acc[nt], 0,0,0);
        }
        if (doY) {
          accy = MFMA16(ah, woY[i], accy, 0,0,0);
          accy = MFMA16(al, woY[i], accy, 0,0,0);
        }
      }
      f32x4 ax[4] = {{0,0,0,0},{0,0,0,0},{0,0,0,0},{0,0,0,0}};
      if (doX) iin_partials(t + 1, ax);

      // ---- partials -> LDS scratch (D rows 0..3 = batches, on lanes 0..15)
      if (l < 16) {
#pragma unroll
        for (int nt = 0; nt < 4; ++nt)
#pragma unroll
          for (int q = 0; q < 4; ++q) sch[slotP][v][q][nt*16 + l] = acc[nt][q];
        if (doX) {
#pragma unroll
          for (int nt = 0; nt < 4; ++nt)
#pragma unroll
            for (int q = 0; q < 4; ++q) scx[v][q][nt*16 + l] = ax[nt][q];
        }
        if (doY) {
#pragma unroll
          for (int q = 0; q < 4; ++q) scy[v][q][l] = accy[q];
        }
      }
      __syncthreads();

      // ---- distributed epilogue: wave v<4 owns batch vb (64 lanes = 64 j)
      if (v < 4) {
        float ir = 0.f;
#pragma unroll
        for (int kp = 0; kp < 8; ++kp) ir += sch[slotP][kp][vb][l];
        const float z  = (ir - mu_s) * sgi_s;
        const float f  = 1.0f / (1.0f + __expf(-z));
        const float dh = -al_s*hold_s + be_s*f*(iin4 + ir);
        const float hn = hold_s + tsc*dh*ti_s;
        hold_s = hn;
        store_h(hn, slotP, tagP);
        if (doX) {
          float s = wib_s;
#pragma unroll
          for (int kp = 0; kp < 8; ++kp) s += scx[kp][vb][l];
          iin_nx = s;
        }
        if (u == 5) {
          if (t + 1 < S_DIM) {
            tsc = tspan[(size_t)gb_e*S_DIM + t + 1] * (1.0f/6.0f);
            iin4 = iin_nx;
          } else {
            out[OUT_Y_TOTAL + ((size_t)gb_e << 10) + gj] = hn;
          }
        }
      } else if (v == 4 && doY && t > 0) {
        // y(t-1) reduce + store: lane -> (b = l>>4, oc = l&15)
        const int b = l >> 4, oc = l & 15;
        float s = Wob[w*16 + oc];
#pragma unroll
        for (int kp = 0; kp < 8; ++kp) s += scy[kp][b][oc];
        out[((size_t)(b0g + b)*S_DIM + (t-1))*OUT_DIM + w*16 + oc] = s;
      }
    }
  }

  // ---- tail: y(S-1) from final h (phase 1536)
  {
    const unsigned slotC = (p-1) & 1, tagC = (p-1) & 0xFFFu;
    s16x8 woY[4];
    load_wout(woY);
    u32x4 q0,q1,q2,q3,q4,q5,q6,q7;
    acquire(slotC, tagC, q0,q1,q2,q3,q4,q5,q6,q7);
    f32x4 accy = {0.f,0.f,0.f,0.f};
#pragma unroll
    for (int i = 0; i < 4; ++i) {
      u32x4 qa = (i==0) ? q0 : (i==1) ? q2 : (i==2) ? q4 : q6;
      u32x4 qb = (i==0) ? q1 : (i==1) ? q3 : (i==2) ? q5 : q7;
      s16x8 ah = pack_hi(qa, qb), al = pack_lo(qa, qb);
      accy = MFMA16(ah, woY[i], accy, 0,0,0);
      accy = MFMA16(al, woY[i], accy, 0,0,0);
    }
    if (l < 16) {
#pragma unroll
      for (int q = 0; q < 4; ++q) scy[v][q][l] = accy[q];
    }
    __syncthreads();
    if (v == 4) {
      const int b = l >> 4, oc = l & 15;
      float s = Wob[w*16 + oc];
#pragma unroll
      for (int kp = 0; kp < 8; ++kp) s += scy[kp][b][oc];
      out[((size_t)(b0g + b)*S_DIM + (S_DIM-1))*OUT_DIM + w*16 + oc] = s;
    }
  }
}

extern "C" void kernel_launch(void* const* d_in, const int* in_sizes, int n_in,
                              void* d_out, int out_size, void* d_ws, size_t ws_size,
                              hipStream_t stream) {
  const float* x    = (const float*)d_in[0];
  const float* h0   = (const float*)d_in[1];
  const float* ts   = (const float*)d_in[2];
  const float* tau  = (const float*)d_in[3];
  const float* Wiw  = (const float*)d_in[4];
  const float* Wib  = (const float*)d_in[5];
  const float* Wrw  = (const float*)d_in[6];
  const float* msk  = (const float*)d_in[7];
  const float* Wow  = (const float*)d_in[8];
  const float* Wob  = (const float*)d_in[9];
  const float* alp  = (const float*)d_in[10];
  const float* bet  = (const float*)d_in[11];
  const float* mu   = (const float*)d_in[12];
  const float* sg   = (const float*)d_in[13];
  float* out = (float*)d_out;
  unsigned* hb = (unsigned*)d_ws;   // 2 slots x 256KB tagged h exchange

  // poison all tags (decode 4095 = never valid) -> replay-deterministic
  hipMemsetAsync(hb, 0xFF, 2*SLOT_STRIDE*sizeof(unsigned), stream);

  void* args[] = { (void*)&x, (void*)&h0, (void*)&ts, (void*)&tau,
                   (void*)&Wiw, (void*)&Wib, (void*)&Wrw, (void*)&msk,
                   (void*)&Wow, (void*)&Wob, (void*)&alp, (void*)&bet,
                   (void*)&mu, (void*)&sg, (void*)&out, (void*)&hb };
  hipLaunchCooperativeKernel((const void*)ltc_kernel, dim3(NWG), dim3(NTHREADS),
                             args, 0, stream);
}

// Round 13
// 4756.208 us; speedup vs baseline: 2.1267x; 1.1719x over previous
//
#include <hip/hip_runtime.h>

#define IN_DIM   512
#define H_DIM    1024
#define OUT_DIM  256
#define B_DIM    64
#define S_DIM    256
#define EPS_F    1e-8f

#define BPG      4      // batches per group
#define JPW      64     // j-columns per WG
#define NTHREADS 512
#define NWG      256    // one WG per CU (LDS 94KB forces it)
#define SLOT_STRIDE 65536   // u32 elements per exchange slot

#define OUT_Y_TOTAL ((size_t)B_DIM*S_DIM*OUT_DIM)

typedef float    f32x4 __attribute__((ext_vector_type(4)));
typedef unsigned u32x4 __attribute__((ext_vector_type(4)));
typedef short    s16x8 __attribute__((ext_vector_type(8)));

#define MFMA16 __builtin_amdgcn_mfma_f32_16x16x32_bf16

union B8 { unsigned u[4]; s16x8 v; };

// round-to-nearest bf16 pack of 8 floats (weights: rel err <= 2^-10)
__device__ __forceinline__ s16x8 round_bf16x8(f32x4 f0, f32x4 f1) {
  B8 H;
  float fv[8];
#pragma unroll
  for (int e = 0; e < 4; ++e) { fv[e] = f0[e]; fv[e+4] = f1[e]; }
#pragma unroll
  for (int d = 0; d < 4; ++d) {
    unsigned u0 = __float_as_uint(fv[2*d])   + 0x8000u;
    unsigned u1 = __float_as_uint(fv[2*d+1]) + 0x8000u;
    H.u[d] = (u0 >> 16) | (u1 & 0xFFFF0000u);
  }
  return H.v;
}

// split f32 -> (bf16 hi, bf16 lo) by truncation (A-side: x, h exchange)
__device__ __forceinline__ void split_bf16(f32x4 f0, f32x4 f1, s16x8* hi, s16x8* lo) {
  B8 H, L;
  float fv[8];
#pragma unroll
  for (int e = 0; e < 4; ++e) { fv[e] = f0[e]; fv[e+4] = f1[e]; }
#pragma unroll
  for (int d = 0; d < 4; ++d) {
    unsigned u0 = __float_as_uint(fv[2*d]);
    unsigned u1 = __float_as_uint(fv[2*d+1]);
    unsigned t0 = u0 & 0xffff0000u, t1 = u1 & 0xffff0000u;
    H.u[d] = (u0 >> 16) | t1;
    L.u[d] = ((__float_as_uint(fv[2*d]   - __uint_as_float(t0))) >> 16)
           | ((__float_as_uint(fv[2*d+1] - __uint_as_float(t1))) & 0xffff0000u);
  }
  *hi = H.v; *lo = L.v;
}

// 12-bit phase tag spread 3 bits per word of each 16B granule (R7-proven).
__device__ __forceinline__ unsigned dec_tag(u32x4 q) {
  return (q.x & 7u) | ((q.y & 7u) << 3) | ((q.z & 7u) << 6) | ((q.w & 7u) << 9);
}
__device__ __forceinline__ s16x8 pack_hi(u32x4 a, u32x4 b) {
  B8 t;
  t.u[0] = (a.y & 0xFFFF0000u) | (a.x >> 16);
  t.u[1] = (a.w & 0xFFFF0000u) | (a.z >> 16);
  t.u[2] = (b.y & 0xFFFF0000u) | (b.x >> 16);
  t.u[3] = (b.w & 0xFFFF0000u) | (b.z >> 16);
  return t.v;
}
__device__ __forceinline__ s16x8 pack_lo(u32x4 a, u32x4 b) {
  B8 t;   // strip 3 stolen tag bits from every residual word
  t.u[0] = ((a.y & 0xFFF8u) << 16) | (a.x & 0xFFF8u);
  t.u[1] = ((a.w & 0xFFF8u) << 16) | (a.z & 0xFFF8u);
  t.u[2] = ((b.y & 0xFFF8u) << 16) | (b.x & 0xFFF8u);
  t.u[3] = ((b.w & 0xFFF8u) << 16) | (b.z & 0xFFF8u);
  return t.v;
}

__global__ void __launch_bounds__(NTHREADS)
ltc_kernel(const float* __restrict__ x, const float* __restrict__ h0,
           const float* __restrict__ tspan, const float* __restrict__ tau,
           const float* __restrict__ Wiw, const float* __restrict__ Wib,
           const float* __restrict__ Wrw, const float* __restrict__ wmask,
           const float* __restrict__ Wow, const float* __restrict__ Wob,
           const float* __restrict__ alpha_p, const float* __restrict__ beta_p,
           const float* __restrict__ mu_p, const float* __restrict__ sigma_p,
           float* __restrict__ out, unsigned* __restrict__ hb)
{
  __shared__ float sch[2][8][4][68];       // [slot][kp][b][j] h partials (17408 B)
  __shared__ float scx[8][4][68];          // iin partials (8704 B)
  __shared__ float scy[8][4][20];          // y partials (2560 B)
  __shared__ __align__(16) char winlds[65536];  // Win bf16 frags (94KB total -> 1 WG/CU)

  const int tid = threadIdx.x;
  const int wg  = blockIdx.x;
  const int g   = wg >> 4;          // group: 4 batches (16 groups)
  const int w   = wg & 15;          // j-slice (64 cols) within group
  const int b0g = g * BPG;
  const int jw0 = w * JPW;
  const int l   = tid & 63;
  const int v   = tid >> 6;         // wave id = K-part (k in [128v,128v+128))
  const int vb  = v & 3;
  const int gb_e = b0g + vb;        // epilogue batch (waves 0..3 only)
  const int gj  = jw0 + l;          // epilogue column (1/lane)

  // ---- W_rec B-frags (masked, ROUNDED bf16-hi) -> registers (64 VGPR)
  s16x8 wbh[4][4];
#pragma unroll
  for (int i = 0; i < 4; ++i) {
    const int k0 = v*128 + i*32 + ((l >> 4) << 3);
#pragma unroll
    for (int nt = 0; nt < 4; ++nt) {
      const size_t go = (size_t)(jw0 + nt*16 + (l & 15))*H_DIM + k0;
      f32x4 w0 = *(const f32x4*)(Wrw + go)     * *(const f32x4*)(wmask + go);
      f32x4 w1 = *(const f32x4*)(Wrw + go + 4) * *(const f32x4*)(wmask + go + 4);
      wbh[i][nt] = round_bf16x8(w0, w1);
    }
  }

  // ---- Win bf16 fragments -> LDS once (wave-private region; no barrier needed)
#pragma unroll
  for (int i2 = 0; i2 < 2; ++i2)
#pragma unroll
    for (int nt = 0; nt < 4; ++nt) {
      const float* wp = Wiw + (size_t)(jw0 + nt*16 + (l & 15))*IN_DIM
                      + v*64 + i2*32 + ((l >> 4) << 3);
      s16x8 wh = round_bf16x8(*(const f32x4*)wp, *(const f32x4*)(wp + 4));
      *(s16x8*)(winlds + ((v*2 + i2)*4 + nt)*1024 + l*16) = wh;
    }

  // ---- per-thread epilogue state: (b = vb, j = lane), scalar
  const float mu_s  = mu_p[gj];
  const float sgi_s = 1.0f / (sigma_p[gj] + EPS_F);
  const float al_s  = alpha_p[gj];
  const float be_s  = beta_p[gj];
  const float ti_s  = 1.0f / tau[gj];
  const float wib_s = Wib[gj];
  float hold_s = h0[((size_t)gb_e << 10) + gj];
  float tsc = tspan[(size_t)gb_e*S_DIM] * (1.0f/6.0f);

  // ---- publish one h element (tag piece by j%4; R7 encoding)
  auto store_h = [&](float hn, unsigned slot, unsigned tag) {
    unsigned uh = __float_as_uint(hn) & 0xFFFF0000u;
    float r = hn - __uint_as_float(uh);
    unsigned e = (uh | (__float_as_uint(r) >> 16)) & ~7u;
    e |= (tag >> (3*(l & 3))) & 7u;
    unsigned* dst = hb + slot*SLOT_STRIDE + ((unsigned)gb_e << 10) + (unsigned)gj;
    asm volatile("global_store_dword %0, %1, off sc0 sc1"
                 :: "v"(dst), "v"(e) : "memory");
  };

  if (v < 4) store_h(hold_s, 0u, 0u);   // phase 0: h0 -> slot 0, tag 0

  // ---- two-phase acquire: 16B sentinels (q0: producer WG 2v, q4: WG 2v+1),
  // then bulk pull with per-granule tag verify (stores land together -> rare loop)
  auto acquire = [&](unsigned slotC, unsigned tagC,
                     u32x4& q0, u32x4& q1, u32x4& q2, u32x4& q3,
                     u32x4& q4, u32x4& q5, u32x4& q6, u32x4& q7) {
    const unsigned* ap = hb + slotC*SLOT_STRIDE
                       + ((unsigned)(b0g + (l & 15)) << 10)
                       + (unsigned)(v*128 + ((l >> 4) << 3));
    for (;;) {   // phase 1: sentinels only (32 B/wave/round)
      int ok;
      if ((l & 15) < 4) {
        asm volatile(
          "global_load_dwordx4 %0, %2, off sc0 sc1\n\t"
          "global_load_dwordx4 %1, %2, off offset:256 sc0 sc1\n\t"
          "s_waitcnt vmcnt(0)"
          : "=&v"(q0), "=&v"(q4) : "v"(ap) : "memory");
        ok = (dec_tag(q0) == tagC) & (dec_tag(q4) == tagC);
      } else ok = 1;
      if (__all(ok)) break;
      __builtin_amdgcn_s_sleep(1);
    }
    for (;;) {   // phase 2: bulk pull + verify
      int ok;
      if ((l & 15) < 4) {
        asm volatile(
          "global_load_dwordx4 %0, %6, off offset:16 sc0 sc1\n\t"
          "global_load_dwordx4 %1, %6, off offset:128 sc0 sc1\n\t"
          "global_load_dwordx4 %2, %6, off offset:144 sc0 sc1\n\t"
          "global_load_dwordx4 %3, %6, off offset:272 sc0 sc1\n\t"
          "global_load_dwordx4 %4, %6, off offset:384 sc0 sc1\n\t"
          "global_load_dwordx4 %5, %6, off offset:400 sc0 sc1\n\t"
          "s_waitcnt vmcnt(0)"
          : "=&v"(q1), "=&v"(q2), "=&v"(q3), "=&v"(q5), "=&v"(q6), "=&v"(q7)
          : "v"(ap) : "memory");
        ok = (dec_tag(q1) == tagC) & (dec_tag(q2) == tagC) & (dec_tag(q3) == tagC) &
             (dec_tag(q5) == tagC) & (dec_tag(q6) == tagC) & (dec_tag(q7) == tagC);
      } else ok = 1;
      if (__all(ok)) break;
      __builtin_amdgcn_s_sleep(1);
    }
  };

  // ---- iin partial MFMA (x split hi/lo; Win bf16 frags from LDS)
  auto iin_partials = [&](int tt, f32x4 ax[4]) {
    const int r = l & 15, c = (l >> 4) << 3;
    const float* xp = x + ((size_t)(b0g + (r & 3))*S_DIM + tt)*IN_DIM + v*64 + c;
    f32x4 xq0 = *(const f32x4*)xp,        xq1 = *(const f32x4*)(xp + 4);
    f32x4 xq2 = *(const f32x4*)(xp + 32), xq3 = *(const f32x4*)(xp + 36);
#pragma unroll
    for (int i2 = 0; i2 < 2; ++i2) {
      s16x8 xh, xl;
      split_bf16(i2 ? xq2 : xq0, i2 ? xq3 : xq1, &xh, &xl);
#pragma unroll
      for (int nt = 0; nt < 4; ++nt) {
        s16x8 wh = *(const s16x8*)(winlds + ((v*2 + i2)*4 + nt)*1024 + l*16);
        ax[nt] = MFMA16(xh, wh, ax[nt], 0,0,0);
        ax[nt] = MFMA16(xl, wh, ax[nt], 0,0,0);
      }
    }
  };

  // ---- Wout B-frags on demand, ROUNDED hi only
  auto load_wout = [&](s16x8 woY[4]) {
#pragma unroll
    for (int i = 0; i < 4; ++i) {
      const int k0 = v*128 + i*32 + ((l >> 4) << 3);
      const size_t go = (size_t)(w*16 + (l & 15))*H_DIM + k0;
      woY[i] = round_bf16x8(*(const f32x4*)(Wow + go), *(const f32x4*)(Wow + go + 4));
    }
  };

  // ---- pre-loop: iin(0) -> iin4 register (threads of waves 0..3)
  float iin4 = 0.f, iin_nx = 0.f;
  {
    f32x4 ax[4] = {{0,0,0,0},{0,0,0,0},{0,0,0,0},{0,0,0,0}};
    iin_partials(0, ax);
    if (l < 16) {
#pragma unroll
      for (int nt = 0; nt < 4; ++nt)
#pragma unroll
        for (int q = 0; q < 4; ++q) scx[v][q][nt*16 + l] = ax[nt][q];
    }
    __syncthreads();
    if (v < 4) {
      float s = wib_s;
#pragma unroll
      for (int kp = 0; kp < 8; ++kp) s += scx[kp][vb][l];
      iin4 = s;
    }
    __syncthreads();
  }

  unsigned p = 1;
#pragma unroll 1
  for (int t = 0; t < S_DIM; ++t) {
#pragma unroll 1
    for (int u = 0; u < 6; ++u, ++p) {
      const unsigned slotC = (p-1) & 1, tagC = (p-1) & 0xFFFu;
      const unsigned slotP = p & 1,     tagP = p & 0xFFFu;
      const bool doY = (u == 0);
      const bool doX = (u == 3) && (t + 1 < S_DIM);

      s16x8 woY[4];
      if (doY) load_wout(woY);      // cached; overlaps the poll below

      u32x4 q0,q1,q2,q3,q4,q5,q6,q7;
      acquire(slotC, tagC, q0,q1,q2,q3,q4,q5,q6,q7);

      // ---- MFMA: 2-term (h_hi*W + h_lo*W), rounded-bf16 W from registers
      f32x4 acc[4] = {{0,0,0,0},{0,0,0,0},{0,0,0,0},{0,0,0,0}};
      f32x4 accy = {0.f,0.f,0.f,0.f};
#pragma unroll
      for (int i = 0; i < 4; ++i) {
        u32x4 qa = (i==0) ? q0 : (i==1) ? q2 : (i==2) ? q4 : q6;
        u32x4 qb = (i==0) ? q1 : (i==1) ? q3 : (i==2) ? q5 : q7;
        s16x8 ah = pack_hi(qa, qb), al = pack_lo(qa, qb);
#pragma unroll
        for (int nt = 0; nt < 4; ++nt) {
          acc[nt] = MFMA16(ah, wbh[i][nt], acc[nt], 0,0,0);
          acc[nt] = MFMA16(al, wbh[i][nt], acc[nt], 0,0,0);
        }
        if (doY) {
          accy = MFMA16(ah, woY[i], accy, 0,0,0);
          accy = MFMA16(al, woY[i], accy, 0,0,0);
        }
      }
      f32x4 ax[4] = {{0,0,0,0},{0,0,0,0},{0,0,0,0},{0,0,0,0}};
      if (doX) iin_partials(t + 1, ax);

      // ---- partials -> LDS scratch (D rows 0..3 = batches, on lanes 0..15)
      if (l < 16) {
#pragma unroll
        for (int nt = 0; nt < 4; ++nt)
#pragma unroll
          for (int q = 0; q < 4; ++q) sch[slotP][v][q][nt*16 + l] = acc[nt][q];
        if (doX) {
#pragma unroll
          for (int nt = 0; nt < 4; ++nt)
#pragma unroll
            for (int q = 0; q < 4; ++q) scx[v][q][nt*16 + l] = ax[nt][q];
        }
        if (doY) {
#pragma unroll
          for (int q = 0; q < 4; ++q) scy[v][q][l] = accy[q];
        }
      }
      __syncthreads();

      // ---- distributed epilogue: wave v<4 owns batch vb (64 lanes = 64 j)
      if (v < 4) {
        float ir = 0.f;
#pragma unroll
        for (int kp = 0; kp < 8; ++kp) ir += sch[slotP][kp][vb][l];
        const float z  = (ir - mu_s) * sgi_s;
        const float f  = 1.0f / (1.0f + __expf(-z));
        const float dh = -al_s*hold_s + be_s*f*(iin4 + ir);
        const float hn = hold_s + tsc*dh*ti_s;
        hold_s = hn;
        store_h(hn, slotP, tagP);
        if (doX) {
          float s = wib_s;
#pragma unroll
          for (int kp = 0; kp < 8; ++kp) s += scx[kp][vb][l];
          iin_nx = s;
        }
        if (u == 5) {
          if (t + 1 < S_DIM) {
            tsc = tspan[(size_t)gb_e*S_DIM + t + 1] * (1.0f/6.0f);
            iin4 = iin_nx;
          } else {
            out[OUT_Y_TOTAL + ((size_t)gb_e << 10) + gj] = hn;
          }
        }
      } else if (v == 4 && doY && t > 0) {
        // y(t-1) reduce + store: lane -> (b = l>>4, oc = l&15)
        const int b = l >> 4, oc = l & 15;
        float s = Wob[w*16 + oc];
#pragma unroll
        for (int kp = 0; kp < 8; ++kp) s += scy[kp][b][oc];
        out[((size_t)(b0g + b)*S_DIM + (t-1))*OUT_DIM + w*16 + oc] = s;
      }
    }
  }

  // ---- tail: y(S-1) from final h (phase 1536)
  {
    const unsigned slotC = (p-1) & 1, tagC = (p-1) & 0xFFFu;
    s16x8 woY[4];
    load_wout(woY);
    u32x4 q0,q1,q2,q3,q4,q5,q6,q7;
    acquire(slotC, tagC, q0,q1,q2,q3,q4,q5,q6,q7);
    f32x4 accy = {0.f,0.f,0.f,0.f};
#pragma unroll
    for (int i = 0; i < 4; ++i) {
      u32x4 qa = (i==0) ? q0 : (i==1) ? q2 : (i==2) ? q4 : q6;
      u32x4 qb = (i==0) ? q1 : (i==1) ? q3 : (i==2) ? q5 : q7;
      s16x8 ah = pack_hi(qa, qb), al = pack_lo(qa, qb);
      accy = MFMA16(ah, woY[i], accy, 0,0,0);
      accy = MFMA16(al, woY[i], accy, 0,0,0);
    }
    if (l < 16) {
#pragma unroll
      for (int q = 0; q < 4; ++q) scy[v][q][l] = accy[q];
    }
    __syncthreads();
    if (v == 4) {
      const int b = l >> 4, oc = l & 15;
      float s = Wob[w*16 + oc];
#pragma unroll
      for (int kp = 0; kp < 8; ++kp) s += scy[kp][b][oc];
      out[((size_t)(b0g + b)*S_DIM + (S_DIM-1))*OUT_DIM + w*16 + oc] = s;
    }
  }
}

extern "C" void kernel_launch(void* const* d_in, const int* in_sizes, int n_in,
                              void* d_out, int out_size, void* d_ws, size_t ws_size,
                              hipStream_t stream) {
  const float* x    = (const float*)d_in[0];
  const float* h0   = (const float*)d_in[1];
  const float* ts   = (const float*)d_in[2];
  const float* tau  = (const float*)d_in[3];
  const float* Wiw  = (const float*)d_in[4];
  const float* Wib  = (const float*)d_in[5];
  const float* Wrw  = (const float*)d_in[6];
  const float* msk  = (const float*)d_in[7];
  const float* Wow  = (const float*)d_in[8];
  const float* Wob  = (const float*)d_in[9];
  const float* alp  = (const float*)d_in[10];
  const float* bet  = (const float*)d_in[11];
  const float* mu   = (const float*)d_in[12];
  const float* sg   = (const float*)d_in[13];
  float* out = (float*)d_out;
  unsigned* hb = (unsigned*)d_ws;   // 2 slots x 256KB tagged h exchange

  // poison all tags (decode 4095 = never valid) -> replay-deterministic
  hipMemsetAsync(hb, 0xFF, 2*SLOT_STRIDE*sizeof(unsigned), stream);

  void* args[] = { (void*)&x, (void*)&h0, (void*)&ts, (void*)&tau,
                   (void*)&Wiw, (void*)&Wib, (void*)&Wrw, (void*)&msk,
                   (void*)&Wow, (void*)&Wob, (void*)&alp, (void*)&bet,
                   (void*)&mu, (void*)&sg, (void*)&out, (void*)&hb };
  hipLaunchCooperativeKernel((const void*)ltc_kernel, dim3(NWG), dim3(NTHREADS),
                             args, 0, stream);
}

// Round 14
// 4648.389 us; speedup vs baseline: 2.1760x; 1.0232x over previous
//
#include <hip/hip_runtime.h>

#define IN_DIM   512
#define H_DIM    1024
#define OUT_DIM  256
#define B_DIM    64
#define S_DIM    256
#define EPS_F    1e-8f

#define BPG      4      // batches per group
#define JPW      64     // j-columns per WG
#define NTHREADS 512
#define NWG      256    // one WG per CU (LDS 94KB forces it)
#define SLOT_STRIDE 65536   // u32 elements per exchange slot

#define OUT_Y_TOTAL ((size_t)B_DIM*S_DIM*OUT_DIM)

typedef float    f32x4 __attribute__((ext_vector_type(4)));
typedef unsigned u32x4 __attribute__((ext_vector_type(4)));
typedef short    s16x8 __attribute__((ext_vector_type(8)));

#define MFMA16 __builtin_amdgcn_mfma_f32_16x16x32_bf16

union B8 { unsigned u[4]; s16x8 v; };

// round-to-nearest bf16 pack of 8 floats (weights: rel err <= 2^-10)
__device__ __forceinline__ s16x8 round_bf16x8(f32x4 f0, f32x4 f1) {
  B8 H;
  float fv[8];
#pragma unroll
  for (int e = 0; e < 4; ++e) { fv[e] = f0[e]; fv[e+4] = f1[e]; }
#pragma unroll
  for (int d = 0; d < 4; ++d) {
    unsigned u0 = __float_as_uint(fv[2*d])   + 0x8000u;
    unsigned u1 = __float_as_uint(fv[2*d+1]) + 0x8000u;
    H.u[d] = (u0 >> 16) | (u1 & 0xFFFF0000u);
  }
  return H.v;
}

// split f32 -> (bf16 hi, bf16 lo) by truncation (A-side: x, h exchange)
__device__ __forceinline__ void split_bf16(f32x4 f0, f32x4 f1, s16x8* hi, s16x8* lo) {
  B8 H, L;
  float fv[8];
#pragma unroll
  for (int e = 0; e < 4; ++e) { fv[e] = f0[e]; fv[e+4] = f1[e]; }
#pragma unroll
  for (int d = 0; d < 4; ++d) {
    unsigned u0 = __float_as_uint(fv[2*d]);
    unsigned u1 = __float_as_uint(fv[2*d+1]);
    unsigned t0 = u0 & 0xffff0000u, t1 = u1 & 0xffff0000u;
    H.u[d] = (u0 >> 16) | t1;
    L.u[d] = ((__float_as_uint(fv[2*d]   - __uint_as_float(t0))) >> 16)
           | ((__float_as_uint(fv[2*d+1] - __uint_as_float(t1))) & 0xffff0000u);
  }
  *hi = H.v; *lo = L.v;
}

// 12-bit phase tag spread 3 bits per word of each 16B granule (R7-proven).
__device__ __forceinline__ unsigned dec_tag(u32x4 q) {
  return (q.x & 7u) | ((q.y & 7u) << 3) | ((q.z & 7u) << 6) | ((q.w & 7u) << 9);
}
__device__ __forceinline__ s16x8 pack_hi(u32x4 a, u32x4 b) {
  B8 t;
  t.u[0] = (a.y & 0xFFFF0000u) | (a.x >> 16);
  t.u[1] = (a.w & 0xFFFF0000u) | (a.z >> 16);
  t.u[2] = (b.y & 0xFFFF0000u) | (b.x >> 16);
  t.u[3] = (b.w & 0xFFFF0000u) | (b.z >> 16);
  return t.v;
}
__device__ __forceinline__ s16x8 pack_lo(u32x4 a, u32x4 b) {
  B8 t;   // strip 3 stolen tag bits from every residual word
  t.u[0] = ((a.y & 0xFFF8u) << 16) | (a.x & 0xFFF8u);
  t.u[1] = ((a.w & 0xFFF8u) << 16) | (a.z & 0xFFF8u);
  t.u[2] = ((b.y & 0xFFF8u) << 16) | (b.x & 0xFFF8u);
  t.u[3] = ((b.w & 0xFFF8u) << 16) | (b.z & 0xFFF8u);
  return t.v;
}

__global__ void __launch_bounds__(NTHREADS)
ltc_kernel(const float* __restrict__ x, const float* __restrict__ h0,
           const float* __restrict__ tspan, const float* __restrict__ tau,
           const float* __restrict__ Wiw, const float* __restrict__ Wib,
           const float* __restrict__ Wrw, const float* __restrict__ wmask,
           const float* __restrict__ Wow, const float* __restrict__ Wob,
           const float* __restrict__ alpha_p, const float* __restrict__ beta_p,
           const float* __restrict__ mu_p, const float* __restrict__ sigma_p,
           float* __restrict__ out, unsigned* __restrict__ hb)
{
  __shared__ float sch[2][8][4][68];       // [slot][kp][b][j] h partials
  __shared__ float scx[8][4][68];          // iin partials
  __shared__ float scy[8][4][20];          // y partials
  __shared__ __align__(16) char winlds[65536];  // Win bf16 frags (94KB -> 1 WG/CU)

  const int tid = threadIdx.x;
  const int wg  = blockIdx.x;
  const int g   = wg >> 4;          // group: 4 batches (16 groups)
  const int w   = wg & 15;          // j-slice (64 cols) within group
  const int b0g = g * BPG;
  const int jw0 = w * JPW;
  const int l   = tid & 63;
  const int v   = tid >> 6;         // wave id = K-part (k in [128v,128v+128))
  const int vb  = v & 3;
  const int gb_e = b0g + vb;        // epilogue batch (waves 0..3 only)
  const int gj  = jw0 + l;          // epilogue column (1/lane)

  // ---- W_rec B-frags (masked, ROUNDED bf16-hi) -> registers (64 VGPR)
  s16x8 wbh[4][4];
#pragma unroll
  for (int i = 0; i < 4; ++i) {
    const int k0 = v*128 + i*32 + ((l >> 4) << 3);
#pragma unroll
    for (int nt = 0; nt < 4; ++nt) {
      const size_t go = (size_t)(jw0 + nt*16 + (l & 15))*H_DIM + k0;
      f32x4 w0 = *(const f32x4*)(Wrw + go)     * *(const f32x4*)(wmask + go);
      f32x4 w1 = *(const f32x4*)(Wrw + go + 4) * *(const f32x4*)(wmask + go + 4);
      wbh[i][nt] = round_bf16x8(w0, w1);
    }
  }

  // ---- Win bf16 fragments -> LDS once (wave-private region; no barrier needed)
#pragma unroll
  for (int i2 = 0; i2 < 2; ++i2)
#pragma unroll
    for (int nt = 0; nt < 4; ++nt) {
      const float* wp = Wiw + (size_t)(jw0 + nt*16 + (l & 15))*IN_DIM
                      + v*64 + i2*32 + ((l >> 4) << 3);
      s16x8 wh = round_bf16x8(*(const f32x4*)wp, *(const f32x4*)(wp + 4));
      *(s16x8*)(winlds + ((v*2 + i2)*4 + nt)*1024 + l*16) = wh;
    }

  // ---- per-thread epilogue state: (b = vb, j = lane), scalar
  const float mu_s  = mu_p[gj];
  const float sgi_s = 1.0f / (sigma_p[gj] + EPS_F);
  const float al_s  = alpha_p[gj];
  const float be_s  = beta_p[gj];
  const float ti_s  = 1.0f / tau[gj];
  const float wib_s = Wib[gj];
  float hold_s = h0[((size_t)gb_e << 10) + gj];
  float tsc = tspan[(size_t)gb_e*S_DIM] * (1.0f/6.0f);

  // ---- publish one h element (tag piece by j%4; R7 encoding)
  auto store_h = [&](float hn, unsigned slot, unsigned tag) {
    unsigned uh = __float_as_uint(hn) & 0xFFFF0000u;
    float r = hn - __uint_as_float(uh);
    unsigned e = (uh | (__float_as_uint(r) >> 16)) & ~7u;
    e |= (tag >> (3*(l & 3))) & 7u;
    unsigned* dst = hb + slot*SLOT_STRIDE + ((unsigned)gb_e << 10) + (unsigned)gj;
    asm volatile("global_store_dword %0, %1, off sc0 sc1"
                 :: "v"(dst), "v"(e) : "memory");
  };

  if (v < 4) store_h(hold_s, 0u, 0u);   // phase 0: h0 -> slot 0, tag 0

  // ---- adaptive acquire: round-0 speculative full pull (1 RT when producer
  // already done); on miss, cheap sentinel rounds; then bulk + verify.
  auto acquire = [&](unsigned slotC, unsigned tagC,
                     u32x4& q0, u32x4& q1, u32x4& q2, u32x4& q3,
                     u32x4& q4, u32x4& q5, u32x4& q6, u32x4& q7) {
    const unsigned* ap = hb + slotC*SLOT_STRIDE
                       + ((unsigned)(b0g + (l & 15)) << 10)
                       + (unsigned)(v*128 + ((l >> 4) << 3));
    {  // round 0: all 8 granules speculatively
      int ok;
      if ((l & 15) < 4) {
        asm volatile(
          "global_load_dwordx4 %0, %8, off sc0 sc1\n\t"
          "global_load_dwordx4 %1, %8, off offset:16 sc0 sc1\n\t"
          "global_load_dwordx4 %2, %8, off offset:128 sc0 sc1\n\t"
          "global_load_dwordx4 %3, %8, off offset:144 sc0 sc1\n\t"
          "global_load_dwordx4 %4, %8, off offset:256 sc0 sc1\n\t"
          "global_load_dwordx4 %5, %8, off offset:272 sc0 sc1\n\t"
          "global_load_dwordx4 %6, %8, off offset:384 sc0 sc1\n\t"
          "global_load_dwordx4 %7, %8, off offset:400 sc0 sc1\n\t"
          "s_waitcnt vmcnt(0)"
          : "=&v"(q0), "=&v"(q1), "=&v"(q2), "=&v"(q3),
            "=&v"(q4), "=&v"(q5), "=&v"(q6), "=&v"(q7)
          : "v"(ap) : "memory");
        ok = (dec_tag(q0) == tagC) & (dec_tag(q1) == tagC) &
             (dec_tag(q2) == tagC) & (dec_tag(q3) == tagC) &
             (dec_tag(q4) == tagC) & (dec_tag(q5) == tagC) &
             (dec_tag(q6) == tagC) & (dec_tag(q7) == tagC);
      } else ok = 1;
      if (__all(ok)) return;
    }
    for (;;) {   // sentinel rounds (32 B/wave)
      int ok;
      if ((l & 15) < 4) {
        asm volatile(
          "global_load_dwordx4 %0, %2, off sc0 sc1\n\t"
          "global_load_dwordx4 %1, %2, off offset:256 sc0 sc1\n\t"
          "s_waitcnt vmcnt(0)"
          : "=&v"(q0), "=&v"(q4) : "v"(ap) : "memory");
        ok = (dec_tag(q0) == tagC) & (dec_tag(q4) == tagC);
      } else ok = 1;
      if (__all(ok)) break;
      __builtin_amdgcn_s_sleep(1);
    }
    for (;;) {   // bulk + verify
      int ok;
      if ((l & 15) < 4) {
        asm volatile(
          "global_load_dwordx4 %0, %6, off offset:16 sc0 sc1\n\t"
          "global_load_dwordx4 %1, %6, off offset:128 sc0 sc1\n\t"
          "global_load_dwordx4 %2, %6, off offset:144 sc0 sc1\n\t"
          "global_load_dwordx4 %3, %6, off offset:272 sc0 sc1\n\t"
          "global_load_dwordx4 %4, %6, off offset:384 sc0 sc1\n\t"
          "global_load_dwordx4 %5, %6, off offset:400 sc0 sc1\n\t"
          "s_waitcnt vmcnt(0)"
          : "=&v"(q1), "=&v"(q2), "=&v"(q3), "=&v"(q5), "=&v"(q6), "=&v"(q7)
          : "v"(ap) : "memory");
        ok = (dec_tag(q1) == tagC) & (dec_tag(q2) == tagC) & (dec_tag(q3) == tagC) &
             (dec_tag(q5) == tagC) & (dec_tag(q6) == tagC) & (dec_tag(q7) == tagC);
      } else ok = 1;
      if (__all(ok)) break;
      __builtin_amdgcn_s_sleep(1);
    }
  };

  // ---- iin partial MFMA (x split hi/lo; Win bf16 frags from LDS)
  auto iin_partials = [&](int tt, f32x4 ax[4]) {
    const int r = l & 15, c = (l >> 4) << 3;
    const float* xp = x + ((size_t)(b0g + (r & 3))*S_DIM + tt)*IN_DIM + v*64 + c;
    f32x4 xq0 = *(const f32x4*)xp,        xq1 = *(const f32x4*)(xp + 4);
    f32x4 xq2 = *(const f32x4*)(xp + 32), xq3 = *(const f32x4*)(xp + 36);
#pragma unroll
    for (int i2 = 0; i2 < 2; ++i2) {
      s16x8 xh, xl;
      split_bf16(i2 ? xq2 : xq0, i2 ? xq3 : xq1, &xh, &xl);
#pragma unroll
      for (int nt = 0; nt < 4; ++nt) {
        s16x8 wh = *(const s16x8*)(winlds + ((v*2 + i2)*4 + nt)*1024 + l*16);
        ax[nt] = MFMA16(xh, wh, ax[nt], 0,0,0);
        ax[nt] = MFMA16(xl, wh, ax[nt], 0,0,0);
      }
    }
  };

  // ---- Wout B-frags on demand, ROUNDED hi only
  auto load_wout = [&](s16x8 woY[4]) {
#pragma unroll
    for (int i = 0; i < 4; ++i) {
      const int k0 = v*128 + i*32 + ((l >> 4) << 3);
      const size_t go = (size_t)(w*16 + (l & 15))*H_DIM + k0;
      woY[i] = round_bf16x8(*(const f32x4*)(Wow + go), *(const f32x4*)(Wow + go + 4));
    }
  };

  // ---- pre-loop: iin(0) -> iin4 register (threads of waves 0..3)
  float iin4 = 0.f, iin_nx = 0.f;
  {
    f32x4 ax[4] = {{0,0,0,0},{0,0,0,0},{0,0,0,0},{0,0,0,0}};
    iin_partials(0, ax);
    if (l < 16) {
#pragma unroll
      for (int nt = 0; nt < 4; ++nt)
#pragma unroll
        for (int q = 0; q < 4; ++q) scx[v][q][nt*16 + l] = ax[nt][q];
    }
    __syncthreads();
    if (v < 4) {
      float s = wib_s;
#pragma unroll
      for (int kp = 0; kp < 8; ++kp) s += scx[kp][vb][l];
      iin4 = s;
    }
    __syncthreads();
  }

  unsigned p = 1;
#pragma unroll 1
  for (int t = 0; t < S_DIM; ++t) {
#pragma unroll 1
    for (int u = 0; u < 6; ++u, ++p) {
      const unsigned slotC = (p-1) & 1, tagC = (p-1) & 0xFFFu;
      const unsigned slotP = p & 1,     tagP = p & 0xFFFu;
      const bool doY = (u == 0);
      const bool doX = (u == 3) && (t + 1 < S_DIM);

      s16x8 woY[4];
      if (doY) load_wout(woY);      // cached; overlaps the poll below

      u32x4 q0,q1,q2,q3,q4,q5,q6,q7;
      acquire(slotC, tagC, q0,q1,q2,q3,q4,q5,q6,q7);

      // ---- pre-sync critical path: recurrence MFMAs + scratch ONLY
      f32x4 acc[4] = {{0,0,0,0},{0,0,0,0},{0,0,0,0},{0,0,0,0}};
#pragma unroll
      for (int i = 0; i < 4; ++i) {
        u32x4 qa = (i==0) ? q0 : (i==1) ? q2 : (i==2) ? q4 : q6;
        u32x4 qb = (i==0) ? q1 : (i==1) ? q3 : (i==2) ? q5 : q7;
        s16x8 ah = pack_hi(qa, qb), al = pack_lo(qa, qb);
#pragma unroll
        for (int nt = 0; nt < 4; ++nt) {
          acc[nt] = MFMA16(ah, wbh[i][nt], acc[nt], 0,0,0);
          acc[nt] = MFMA16(al, wbh[i][nt], acc[nt], 0,0,0);
        }
      }
      if (l < 16) {
#pragma unroll
        for (int nt = 0; nt < 4; ++nt)
#pragma unroll
          for (int q = 0; q < 4; ++q) sch[slotP][v][q][nt*16 + l] = acc[nt][q];
      }
      __syncthreads();

      // ---- epilogue first (h-store is what the whole group waits on)
      if (v < 4) {
        float ir = 0.f;
#pragma unroll
        for (int kp = 0; kp < 8; ++kp) ir += sch[slotP][kp][vb][l];
        const float z  = (ir - mu_s) * sgi_s;
        const float f  = 1.0f / (1.0f + __expf(-z));
        const float dh = -al_s*hold_s + be_s*f*(iin4 + ir);
        const float hn = hold_s + tsc*dh*ti_s;
        hold_s = hn;
        store_h(hn, slotP, tagP);
        if (u == 4 && t + 1 < S_DIM) {   // scx written post-sync at u==3
          float s = wib_s;
#pragma unroll
          for (int kp = 0; kp < 8; ++kp) s += scx[kp][vb][l];
          iin_nx = s;
        }
        if (u == 5) {
          if (t + 1 < S_DIM) {
            tsc = tspan[(size_t)gb_e*S_DIM + t + 1] * (1.0f/6.0f);
            iin4 = iin_nx;
          } else {
            out[OUT_Y_TOTAL + ((size_t)gb_e << 10) + gj] = hn;
          }
        }
      } else if (v == 4 && u == 1 && t > 0) {
        // y(t-1): scy written post-sync at u==0, ordered by this phase's barrier
        const int b = l >> 4, oc = l & 15;
        float s = Wob[w*16 + oc];
#pragma unroll
        for (int kp = 0; kp < 8; ++kp) s += scy[kp][b][oc];
        out[((size_t)(b0g + b)*S_DIM + (t-1))*OUT_DIM + w*16 + oc] = s;
      }

      // ---- aux (off the critical path; consumed after a later barrier)
      if (doY) {
        f32x4 accy = {0.f,0.f,0.f,0.f};
#pragma unroll
        for (int i = 0; i < 4; ++i) {
          u32x4 qa = (i==0) ? q0 : (i==1) ? q2 : (i==2) ? q4 : q6;
          u32x4 qb = (i==0) ? q1 : (i==1) ? q3 : (i==2) ? q5 : q7;
          s16x8 ah = pack_hi(qa, qb), al = pack_lo(qa, qb);
          accy = MFMA16(ah, woY[i], accy, 0,0,0);
          accy = MFMA16(al, woY[i], accy, 0,0,0);
        }
        if (l < 16) {
#pragma unroll
          for (int q = 0; q < 4; ++q) scy[v][q][l] = accy[q];
        }
      }
      if (doX) {
        f32x4 ax[4] = {{0,0,0,0},{0,0,0,0},{0,0,0,0},{0,0,0,0}};
        iin_partials(t + 1, ax);
        if (l < 16) {
#pragma unroll
          for (int nt = 0; nt < 4; ++nt)
#pragma unroll
            for (int q = 0; q < 4; ++q) scx[v][q][nt*16 + l] = ax[nt][q];
        }
      }
    }
  }

  // ---- tail: y(S-1) from final h (phase 1536)
  {
    const unsigned slotC = (p-1) & 1, tagC = (p-1) & 0xFFFu;
    s16x8 woY[4];
    load_wout(woY);
    u32x4 q0,q1,q2,q3,q4,q5,q6,q7;
    acquire(slotC, tagC, q0,q1,q2,q3,q4,q5,q6,q7);
    f32x4 accy = {0.f,0.f,0.f,0.f};
#pragma unroll
    for (int i = 0; i < 4; ++i) {
      u32x4 qa = (i==0) ? q0 : (i==1) ? q2 : (i==2) ? q4 : q6;
      u32x4 qb = (i==0) ? q1 : (i==1) ? q3 : (i==2) ? q5 : q7;
      s16x8 ah = pack_hi(qa, qb), al = pack_lo(qa, qb);
      accy = MFMA16(ah, woY[i], accy, 0,0,0);
      accy = MFMA16(al, woY[i], accy, 0,0,0);
    }
    if (l < 16) {
#pragma unroll
      for (int q = 0; q < 4; ++q) scy[v][q][l] = accy[q];
    }
    __syncthreads();
    if (v == 4) {
      const int b = l >> 4, oc = l & 15;
      float s = Wob[w*16 + oc];
#pragma unroll
      for (int kp = 0; kp < 8; ++kp) s += scy[kp][b][oc];
      out[((size_t)(b0g + b)*S_DIM + (S_DIM-1))*OUT_DIM + w*16 + oc] = s;
    }
  }
}

extern "C" void kernel_launch(void* const* d_in, const int* in_sizes, int n_in,
                              void* d_out, int out_size, void* d_ws, size_t ws_size,
                              hipStream_t stream) {
  const float* x    = (const float*)d_in[0];
  const float* h0   = (const float*)d_in[1];
  const float* ts   = (const float*)d_in[2];
  const float* tau  = (const float*)d_in[3];
  const float* Wiw  = (const float*)d_in[4];
  const float* Wib  = (const float*)d_in[5];
  const float* Wrw  = (const float*)d_in[6];
  const float* msk  = (const float*)d_in[7];
  const float* Wow  = (const float*)d_in[8];
  const float* Wob  = (const float*)d_in[9];
  const float* alp  = (const float*)d_in[10];
  const float* bet  = (const float*)d_in[11];
  const float* mu   = (const float*)d_in[12];
  const float* sg   = (const float*)d_in[13];
  float* out = (float*)d_out;
  unsigned* hb = (unsigned*)d_ws;   // 2 slots x 256KB tagged h exchange

  // poison all tags (decode 4095 = never valid) -> replay-deterministic
  hipMemsetAsync(hb, 0xFF, 2*SLOT_STRIDE*sizeof(unsigned), stream);

  void* args[] = { (void*)&x, (void*)&h0, (void*)&ts, (void*)&tau,
                   (void*)&Wiw, (void*)&Wib, (void*)&Wrw, (void*)&msk,
                   (void*)&Wow, (void*)&Wob, (void*)&alp, (void*)&bet,
                   (void*)&mu, (void*)&sg, (void*)&out, (void*)&hb };
  hipLaunchCooperativeKernel((const void*)ltc_kernel, dim3(NWG), dim3(NTHREADS),
                             args, 0, stream);
}